// Round 2
// baseline (1711.412 us; speedup 1.0000x reference)
//
#include <hip/hip_runtime.h>
#include <math.h>

typedef float f4 __attribute__((ext_vector_type(4)));

#define D_MODEL 1024
#define N_HEADS 16
#define D_HEAD  64
#define N_BINS  64
#define D_LAT   8

// ---------------------------------------------------------------------------
// SGEMM (NT): C[M,N] = A[M,K] * W[N,K]^T + bias[N]
// 128x128 block tile, BK=16, 256 threads, 8x8 per thread (col split 4+4).
// ---------------------------------------------------------------------------
__global__ __launch_bounds__(256)
void sgemm_nt_bias(const float* __restrict__ A, const float* __restrict__ W,
                   const float* __restrict__ bias, float* __restrict__ C,
                   int M, int N, int K)
{
    __shared__ __attribute__((aligned(16))) float As[16][132];
    __shared__ __attribute__((aligned(16))) float Bs[16][132];

    const int tid = threadIdx.x;
    const int tx = tid & 15;          // 16 col-groups
    const int ty = tid >> 4;          // 16 row-groups
    const int bm = blockIdx.x * 128;
    const int bn = blockIdx.y * 128;

    const int lrow = tid >> 2;        // 0..63
    const int lk   = (tid & 3) * 4;   // 0,4,8,12

    const float* Ap = A + (size_t)(bm + lrow) * K + lk;
    const float* Wp = W + (size_t)(bn + lrow) * K + lk;

    float acc[8][8];
#pragma unroll
    for (int i = 0; i < 8; i++)
#pragma unroll
        for (int j = 0; j < 8; j++) acc[i][j] = 0.f;

    for (int k0 = 0; k0 < K; k0 += 16) {
        f4 a0 = *(const f4*)(Ap + k0);
        f4 a1 = *(const f4*)(Ap + (size_t)64 * K + k0);
        f4 b0 = *(const f4*)(Wp + k0);
        f4 b1 = *(const f4*)(Wp + (size_t)64 * K + k0);

        __syncthreads();
#pragma unroll
        for (int j = 0; j < 4; j++) {
            As[lk + j][lrow]      = a0[j];
            As[lk + j][lrow + 64] = a1[j];
            Bs[lk + j][lrow]      = b0[j];
            Bs[lk + j][lrow + 64] = b1[j];
        }
        __syncthreads();

#pragma unroll
        for (int k = 0; k < 16; k++) {
            f4 ar0 = *(const f4*)&As[k][ty * 8];
            f4 ar1 = *(const f4*)&As[k][ty * 8 + 4];
            f4 br0 = *(const f4*)&Bs[k][tx * 4];
            f4 br1 = *(const f4*)&Bs[k][64 + tx * 4];
#pragma unroll
            for (int i = 0; i < 8; i++) {
                float av = (i < 4) ? ar0[i] : ar1[i - 4];
#pragma unroll
                for (int j = 0; j < 8; j++) {
                    float bv = (j < 4) ? br0[j] : br1[j - 4];
                    acc[i][j] += av * bv;
                }
            }
        }
    }

    f4 bb0 = *(const f4*)&bias[bn + tx * 4];
    f4 bb1 = *(const f4*)&bias[bn + 64 + tx * 4];
#pragma unroll
    for (int i = 0; i < 8; i++) {
        size_t r = (size_t)(bm + ty * 8 + i);
        f4 o0, o1;
#pragma unroll
        for (int j = 0; j < 4; j++) {
            o0[j] = acc[i][j]     + bb0[j];
            o1[j] = acc[i][j + 4] + bb1[j];
        }
        *(f4*)&C[r * N + bn + tx * 4]      = o0;
        *(f4*)&C[r * N + bn + 64 + tx * 4] = o1;
    }
}

// ---------------------------------------------------------------------------
// Bin assignment + soft aggregation.
// grid = (B*H, CH). Each block processes S/CH = 512 key rows of one (b,h),
// in 8 sub-chunks of 64 rows, accumulating partial weighted_K / weighted_V
// (64x64) and counts (64) into `partials`.
// partial layout per (bh,chunk): [Kacc 4096][Vacc 4096][cnt 64] = 8256 floats.
// ---------------------------------------------------------------------------
__global__ __launch_bounds__(256)
void bin_assign_agg(const float* __restrict__ Kbuf, const float* __restrict__ Vbuf,
                    const float* __restrict__ W_bin, const float* __restrict__ proto,
                    const float* __restrict__ log_tau,
                    float* __restrict__ partials, int B, int S)
{
    const int bh = blockIdx.x;
    const int h  = bh & (N_HEADS - 1);
    const int b  = bh >> 4;
    const int chunk = blockIdx.y;
    const int CH = gridDim.y;
    const int tid = threadIdx.x;

    __shared__ __attribute__((aligned(16))) float Wb[8][64];     // W_bin[l][d]
    __shared__ __attribute__((aligned(16))) float Prt[8][64];    // proto^T [l][n]
    __shared__ __attribute__((aligned(16))) float zsm[64][8];
    __shared__ __attribute__((aligned(16))) float Kt[64][68];
    __shared__ __attribute__((aligned(16))) float Vt[64][68];
    __shared__ __attribute__((aligned(16))) float Pt[64][68];

    if (tid < 128) {
        ((f4*)&Wb[0][0])[tid] = ((const f4*)W_bin)[tid];
    } else {
        int t = tid - 128;
        f4 p = ((const f4*)(proto + (size_t)h * N_BINS * D_LAT))[t];
        int n = t >> 1, l4 = (t & 1) * 4;
        Prt[l4 + 0][n] = p[0];
        Prt[l4 + 1][n] = p[1];
        Prt[l4 + 2][n] = p[2];
        Prt[l4 + 3][n] = p[3];
    }
    const float tau   = fmaxf(expf(log_tau[h]), 1e-3f);
    const float scale = 1.0f / (tau + 1e-8f);

    const int row = tid >> 2, sub = tid & 3;          // 4 lanes per key row
    const int n0 = (tid >> 4) * 4, d0 = (tid & 15) * 4; // 4x4 acc cell

    float accK[4][4], accV[4][4], cnt[4];
#pragma unroll
    for (int i = 0; i < 4; i++) {
        cnt[i] = 0.f;
#pragma unroll
        for (int j = 0; j < 4; j++) { accK[i][j] = 0.f; accV[i][j] = 0.f; }
    }

    const int SC = S / CH;           // 512
    const int s_base = chunk * SC;

    for (int s0 = 0; s0 < SC; s0 += 64) {
        __syncthreads();
        // stage 64 K rows + 64 V rows
#pragma unroll
        for (int q = 0; q < 4; q++) {
            int f  = tid + 256 * q;
            int sl = f >> 4, dd = (f & 15) * 4;
            size_t gi = ((size_t)(b * S + s_base + s0 + sl)) * D_MODEL + h * D_HEAD + dd;
            *(f4*)&Kt[sl][dd] = *(const f4*)&Kbuf[gi];
            *(f4*)&Vt[sl][dd] = *(const f4*)&Vbuf[gi];
        }
        __syncthreads();

        // z[l] = K_row . W_bin[l]  (2 l's per lane)
        {
            const int l0 = sub * 2;
            f4 z0 = {0.f, 0.f, 0.f, 0.f}, z1 = {0.f, 0.f, 0.f, 0.f};
#pragma unroll
            for (int d4 = 0; d4 < 16; d4++) {
                f4 kv = *(const f4*)&Kt[row][d4 * 4];
                f4 w0 = *(const f4*)&Wb[l0][d4 * 4];
                f4 w1 = *(const f4*)&Wb[l0 + 1][d4 * 4];
                z0 += kv * w0;
                z1 += kv * w1;
            }
            zsm[row][l0]     = z0[0] + z0[1] + z0[2] + z0[3];
            zsm[row][l0 + 1] = z1[0] + z1[1] + z1[2] + z1[3];
        }
        __syncthreads();

        // logits + softmax over 64 bins (16 bins per lane, 4-lane reduce)
        {
            float zr[8];
#pragma unroll
            for (int l = 0; l < 8; l++) zr[l] = zsm[row][l];
            f4 lg[4];
#pragma unroll
            for (int q = 0; q < 4; q++) lg[q] = (f4){0.f, 0.f, 0.f, 0.f};
#pragma unroll
            for (int l = 0; l < 8; l++) {
                float zv = zr[l];
#pragma unroll
                for (int q = 0; q < 4; q++) {
                    f4 pr = *(const f4*)&Prt[l][sub * 16 + q * 4];
                    lg[q] += zv * pr;
                }
            }
            float mx = -1e30f;
#pragma unroll
            for (int q = 0; q < 4; q++) {
                lg[q] *= scale;
                mx = fmaxf(mx, fmaxf(fmaxf(lg[q][0], lg[q][1]), fmaxf(lg[q][2], lg[q][3])));
            }
            mx = fmaxf(mx, __shfl_xor(mx, 1));
            mx = fmaxf(mx, __shfl_xor(mx, 2));
            float sum = 0.f;
            f4 pv[4];
#pragma unroll
            for (int q = 0; q < 4; q++) {
#pragma unroll
                for (int e = 0; e < 4; e++) {
                    float ev = expf(lg[q][e] - mx);
                    pv[q][e] = ev;
                    sum += ev;
                }
            }
            sum += __shfl_xor(sum, 1);
            sum += __shfl_xor(sum, 2);
            float inv = 1.0f / sum;
#pragma unroll
            for (int q = 0; q < 4; q++) {
                pv[q] *= inv;
                *(f4*)&Pt[row][sub * 16 + q * 4] = pv[q];
            }
        }
        __syncthreads();

        // outer-product accumulate: acc[n][d] += P[s][n]*K[s][d] (and V), cnt[n] += P[s][n]
#pragma unroll 4
        for (int s = 0; s < 64; s++) {
            f4 pp = *(const f4*)&Pt[s][n0];
            f4 kk = *(const f4*)&Kt[s][d0];
            f4 vv = *(const f4*)&Vt[s][d0];
#pragma unroll
            for (int i = 0; i < 4; i++) {
                float p = pp[i];
#pragma unroll
                for (int j = 0; j < 4; j++) {
                    accK[i][j] += p * kk[j];
                    accV[i][j] += p * vv[j];
                }
            }
            if ((tid & 15) == 0) {
#pragma unroll
                for (int i = 0; i < 4; i++) cnt[i] += pp[i];
            }
        }
    }

    float* base = partials + ((size_t)bh * CH + chunk) * 8256;
#pragma unroll
    for (int i = 0; i < 4; i++) {
#pragma unroll
        for (int j = 0; j < 4; j++) {
            base[(size_t)(n0 + i) * 64 + d0 + j]        = accK[i][j];
            base[4096 + (size_t)(n0 + i) * 64 + d0 + j] = accV[i][j];
        }
        if ((tid & 15) == 0) base[8192 + n0 + i] = cnt[i];
    }
}

// ---------------------------------------------------------------------------
// Reduce partials -> K_binned, V_binned.
// FAITHFUL TO REFERENCE BUG: divides feature d by counts[d] (broadcast of
// [B,H,N,Dh]/[B,H,1,N], valid only because Dh==N).
// ---------------------------------------------------------------------------
__global__ __launch_bounds__(256)
void bin_reduce(const float* __restrict__ partials, float* __restrict__ Kb,
                float* __restrict__ Vb, int CH)
{
    const int bh = blockIdx.x;
    const int tid = threadIdx.x;
    __shared__ float inv_cnt[64];
    const float* base = partials + (size_t)bh * CH * 8256;
    if (tid < 64) {
        float c = 0.f;
        for (int ch = 0; ch < CH; ch++) c += base[(size_t)ch * 8256 + 8192 + tid];
        inv_cnt[tid] = 1.0f / (c + 1e-6f);
    }
    __syncthreads();
    for (int idx = tid; idx < 4096; idx += 256) {
        float k = 0.f, v = 0.f;
        for (int ch = 0; ch < CH; ch++) {
            const float* p = base + (size_t)ch * 8256;
            k += p[idx];
            v += p[4096 + idx];
        }
        float ic = inv_cnt[idx & 63];   // divide by count of FEATURE index d
        Kb[(size_t)bh * 4096 + idx] = k * ic;
        Vb[(size_t)bh * 4096 + idx] = v * ic;
    }
}

// ---------------------------------------------------------------------------
// Bin attention: scores = Q.K_binned^T/8, softmax over 64 bins, ctx = w.V_binned.
// grid = (B*H, S/64). 64 Q-rows per block, 4 lanes per row, 16 bins per lane.
// ---------------------------------------------------------------------------
__global__ __launch_bounds__(256)
void bin_attention(const float* __restrict__ Qbuf, const float* __restrict__ Kb,
                   const float* __restrict__ Vb, float* __restrict__ Ctx,
                   int B, int S)
{
    const int bh = blockIdx.x;
    const int h  = bh & (N_HEADS - 1);
    const int b  = bh >> 4;
    const int tid = threadIdx.x;
    const int row = tid >> 2, sub = tid & 3;

    __shared__ __attribute__((aligned(16))) float Kbs[64][68];
    __shared__ __attribute__((aligned(16))) float Vbs[64][68];
    __shared__ __attribute__((aligned(16))) float Qt[64][68];

    const float* kbp = Kb + (size_t)bh * 4096;
    const float* vbp = Vb + (size_t)bh * 4096;
#pragma unroll
    for (int q = 0; q < 4; q++) {
        int f = tid + 256 * q;
        int n = f >> 4, c = (f & 15) * 4;
        *(f4*)&Kbs[n][c] = *(const f4*)&kbp[(size_t)f * 4];
        *(f4*)&Vbs[n][c] = *(const f4*)&vbp[(size_t)f * 4];
    }
    const int s0 = blockIdx.y * 64;
#pragma unroll
    for (int q = 0; q < 4; q++) {
        int f = tid + 256 * q;
        int sl = f >> 4, dd = (f & 15) * 4;
        size_t gi = ((size_t)(b * S + s0 + sl)) * D_MODEL + h * D_HEAD + dd;
        *(f4*)&Qt[sl][dd] = *(const f4*)&Qbuf[gi];
    }
    __syncthreads();

    // scores for this lane's bins n = 4j+sub
    f4 wa[16];
#pragma unroll
    for (int j = 0; j < 16; j++) wa[j] = (f4){0.f, 0.f, 0.f, 0.f};
    for (int d4 = 0; d4 < 16; d4++) {
        f4 qv = *(const f4*)&Qt[row][d4 * 4];
#pragma unroll
        for (int j = 0; j < 16; j++) {
            f4 kk = *(const f4*)&Kbs[4 * j + sub][d4 * 4];
            wa[j] += qv * kk;
        }
    }
    float w[16];
    float mx = -1e30f;
#pragma unroll
    for (int j = 0; j < 16; j++) {
        w[j] = (wa[j][0] + wa[j][1] + wa[j][2] + wa[j][3]) * 0.125f;
        mx = fmaxf(mx, w[j]);
    }
    mx = fmaxf(mx, __shfl_xor(mx, 1));
    mx = fmaxf(mx, __shfl_xor(mx, 2));
    float sum = 0.f;
#pragma unroll
    for (int j = 0; j < 16; j++) {
        w[j] = expf(w[j] - mx);
        sum += w[j];
    }
    sum += __shfl_xor(sum, 1);
    sum += __shfl_xor(sum, 2);
    float inv = 1.0f / sum;

    // stash normalized weights in Qt (Q is dead) so the ctx loop can be
    // dynamically indexed without spilling register arrays (rule #20)
#pragma unroll
    for (int j = 0; j < 16; j++) Qt[row][4 * j + sub] = w[j] * inv;

    f4 ca[16];
#pragma unroll
    for (int q = 0; q < 16; q++) ca[q] = (f4){0.f, 0.f, 0.f, 0.f};
    for (int j = 0; j < 16; j++) {
        float wn = Qt[row][4 * j + sub];
#pragma unroll
        for (int d4 = 0; d4 < 16; d4++) {
            f4 vv = *(const f4*)&Vbs[4 * j + sub][d4 * 4];
            ca[d4] += wn * vv;
        }
    }

    // reduce-scatter across the 4 lanes of this row:
    // after step1 lane keeps its half, after step2 its final quarter.
    const bool low2 = (sub & 2) == 0;
    f4 halfv[8];
#pragma unroll
    for (int q = 0; q < 8; q++) {
#pragma unroll
        for (int e = 0; e < 4; e++) {
            float send = low2 ? ca[8 + q][e] : ca[q][e];
            float recv = __shfl_xor(send, 2);
            float mine = low2 ? ca[q][e] : ca[8 + q][e];
            halfv[q][e] = mine + recv;
        }
    }
    const bool low1 = (sub & 1) == 0;
    f4 quar[4];
#pragma unroll
    for (int q = 0; q < 4; q++) {
#pragma unroll
        for (int e = 0; e < 4; e++) {
            float send = low1 ? halfv[4 + q][e] : halfv[q][e];
            float recv = __shfl_xor(send, 1);
            float mine = low1 ? halfv[q][e] : halfv[4 + q][e];
            quar[q][e] = mine + recv;
        }
    }

    size_t go = ((size_t)(b * S + s0 + row)) * D_MODEL + h * D_HEAD + sub * 16;
#pragma unroll
    for (int q = 0; q < 4; q++) {
        *(f4*)&Ctx[go + q * 4] = quar[q];
    }
}

// ---------------------------------------------------------------------------
extern "C" void kernel_launch(void* const* d_in, const int* in_sizes, int n_in,
                              void* d_out, int out_size, void* d_ws, size_t ws_size,
                              hipStream_t stream)
{
    (void)n_in; (void)out_size; (void)ws_size;
    const float* x       = (const float*)d_in[0];
    const float* Wq      = (const float*)d_in[1];
    const float* bq      = (const float*)d_in[2];
    const float* Wk      = (const float*)d_in[3];
    const float* bk      = (const float*)d_in[4];
    const float* Wv      = (const float*)d_in[5];
    const float* bv      = (const float*)d_in[6];
    const float* Wo      = (const float*)d_in[7];
    const float* bo      = (const float*)d_in[8];
    const float* W_bin   = (const float*)d_in[9];
    const float* proto   = (const float*)d_in[10];
    const float* log_tau = (const float*)d_in[11];
    float* out = (float*)d_out;

    const int M  = in_sizes[0] / D_MODEL;   // B*S = 16384
    const int S  = 4096;
    const int B  = M / S;                   // 4
    const int BH = B * N_HEADS;             // 64
    const int CH = 8;

    float* ws   = (float*)d_ws;
    float* bufA = ws;                               // K, later Q  (M*1024)
    float* bufB = ws + (size_t)M * D_MODEL;         // V, later ctx (M*1024)
    float* part = bufB + (size_t)M * D_MODEL;       // BH*CH*8256
    float* Kb   = part + (size_t)BH * CH * 8256;    // BH*4096
    float* Vb   = Kb + (size_t)BH * 4096;           // BH*4096

    dim3 gg(M / 128, D_MODEL / 128);

    sgemm_nt_bias<<<gg, 256, 0, stream>>>(x, Wk, bk, bufA, M, D_MODEL, D_MODEL);
    sgemm_nt_bias<<<gg, 256, 0, stream>>>(x, Wv, bv, bufB, M, D_MODEL, D_MODEL);
    bin_assign_agg<<<dim3(BH, CH), 256, 0, stream>>>(bufA, bufB, W_bin, proto,
                                                     log_tau, part, B, S);
    bin_reduce<<<BH, 256, 0, stream>>>(part, Kb, Vb, CH);
    sgemm_nt_bias<<<gg, 256, 0, stream>>>(x, Wq, bq, bufA, M, D_MODEL, D_MODEL);
    bin_attention<<<dim3(BH, S / 64), 256, 0, stream>>>(bufA, Kb, Vb, bufB, B, S);
    sgemm_nt_bias<<<gg, 256, 0, stream>>>(bufB, Wo, bo, out, M, D_MODEL, D_MODEL);
}

// Round 3
// 603.358 us; speedup vs baseline: 2.8365x; 2.8365x over previous
//
#include <hip/hip_runtime.h>
#include <math.h>

typedef float f4 __attribute__((ext_vector_type(4)));
typedef float f32x4 __attribute__((ext_vector_type(4)));
typedef short bf16x8 __attribute__((ext_vector_type(8)));
typedef unsigned int u32x4 __attribute__((ext_vector_type(4)));
typedef unsigned int u32x2 __attribute__((ext_vector_type(2)));

#define D_MODEL 1024
#define N_HEADS 16
#define D_HEAD  64
#define N_BINS  64
#define D_LAT   8

// ---------------------------------------------------------------------------
// bf16 split helpers (RTNE)
// ---------------------------------------------------------------------------
__device__ __forceinline__ unsigned short bf16_rtne(float f) {
    unsigned int u = __builtin_bit_cast(unsigned int, f);
    u += 0x7FFFu + ((u >> 16) & 1u);
    return (unsigned short)(u >> 16);
}
__device__ __forceinline__ float bf16_to_f32(unsigned short h) {
    unsigned int u = ((unsigned int)h) << 16;
    return __builtin_bit_cast(float, u);
}

// fp32 -> (hi, lo) bf16 buffers, 8 elems/thread
__global__ __launch_bounds__(256)
void split_bf16x2(const float* __restrict__ in, unsigned short* __restrict__ hi,
                  unsigned short* __restrict__ lo, int n8)
{
    int i = blockIdx.x * 256 + threadIdx.x;
    if (i >= n8) return;
    const f4* inp = (const f4*)in;
    f4 a = inp[2 * i];
    f4 b = inp[2 * i + 1];
    unsigned short hs[8], ls[8];
#pragma unroll
    for (int j = 0; j < 8; j++) {
        float v = (j < 4) ? a[j] : b[j - 4];
        unsigned short h = bf16_rtne(v);
        hs[j] = h;
        ls[j] = bf16_rtne(v - bf16_to_f32(h));
    }
    u32x4 ho, lv;
#pragma unroll
    for (int j = 0; j < 4; j++) {
        ho[j] = (unsigned int)hs[2 * j] | ((unsigned int)hs[2 * j + 1] << 16);
        lv[j] = (unsigned int)ls[2 * j] | ((unsigned int)ls[2 * j + 1] << 16);
    }
    ((u32x4*)hi)[i] = ho;
    ((u32x4*)lo)[i] = lv;
}

// ---------------------------------------------------------------------------
// Split-bf16 MFMA GEMM (NT): C[M,N] = (Ahi+Alo)[M,K] * (Whi+Wlo)[N,K]^T + bias
// acc = Ahi*Whi + Ahi*Wlo + Alo*Whi (fp32 MFMA accumulate).
// 128x128 tile, BK=32, 256 threads (4 waves, 64x64 out each), double-buffered
// LDS staged via global_load_lds(16B) with chunk-XOR swizzle (both-sides).
// ---------------------------------------------------------------------------
__device__ __forceinline__ void glds16(const unsigned short* g, unsigned short* l) {
    __builtin_amdgcn_global_load_lds((const __attribute__((address_space(1))) void*)g,
                                     (__attribute__((address_space(3))) void*)l,
                                     16, 0, 0);
}

__global__ __launch_bounds__(256)
void gemm_bf16x2_nt(const unsigned short* __restrict__ Ahi, const unsigned short* __restrict__ Alo,
                    const unsigned short* __restrict__ Bhi, const unsigned short* __restrict__ Blo,
                    const float* __restrict__ bias, float* __restrict__ C,
                    int M, int N, int K)
{
    // [dbuf][Ahi,Alo,Bhi,Blo][128 rows * 32 k] bf16 = 64 KB
    __shared__ unsigned short lds[2][4][4096];

    const int tid  = threadIdx.x;
    const int lane = tid & 63;
    const int w    = tid >> 6;
    const int bm   = blockIdx.x * 128;
    const int bn   = blockIdx.y * 128;

    // ---- staging addresses (2 x 1KB segments per wave per tile) ----
    // seg s covers rows [s*16, s*16+16); lane covers 16B at seg_base + lane*16
    // LDS (row r, chunk cpos) holds global k-chunk (cpos ^ (r&3))  [swizzle]
    const int schunk = (lane & 3) ^ ((lane >> 2) & 3);
    size_t gA[2], gB[2];
    int    seg[2];
#pragma unroll
    for (int i = 0; i < 2; i++) {
        int s = i * 4 + w;
        int r = s * 16 + (lane >> 2);
        gA[i]  = (size_t)(bm + r) * K + schunk * 8;
        gB[i]  = (size_t)(bn + r) * K + schunk * 8;
        seg[i] = s * 512;                    // ushort offset of 1KB segment
    }

    // ---- fragment read offsets (ushort units) ----
    // lane reads row (base + (lane&15)), wants k-chunk (lane>>4);
    // swizzled cpos = (lane>>4) ^ (row&3) = (lane>>4) ^ (lane&3)
    const int aoff = (lane & 15) * 32 + (((lane >> 4) ^ (lane & 3)) * 8);
    const int arow = (w >> 1) * 2048;        // wave row-block * 64 rows * 32
    const int brow = (w & 1) * 2048;

    f32x4 acc[4][4];
#pragma unroll
    for (int i = 0; i < 4; i++)
#pragma unroll
        for (int j = 0; j < 4; j++) acc[i][j] = (f32x4){0.f, 0.f, 0.f, 0.f};

    auto stage = [&](int b, int kt) {
#pragma unroll
        for (int i = 0; i < 2; i++) {
            glds16(Ahi + gA[i] + kt, &lds[b][0][seg[i]]);
            glds16(Alo + gA[i] + kt, &lds[b][1][seg[i]]);
            glds16(Bhi + gB[i] + kt, &lds[b][2][seg[i]]);
            glds16(Blo + gB[i] + kt, &lds[b][3][seg[i]]);
        }
    };

    stage(0, 0);
    __syncthreads();

    const int nt = K / 32;
    for (int t = 0; t < nt; t++) {
        const int cur = t & 1;
        if (t + 1 < nt) stage(cur ^ 1, (t + 1) * 32);

        bf16x8 ah[4], al[4], bh[4], bl[4];
#pragma unroll
        for (int f = 0; f < 4; f++) {
            ah[f] = *(const bf16x8*)&lds[cur][0][arow + f * 512 + aoff];
            al[f] = *(const bf16x8*)&lds[cur][1][arow + f * 512 + aoff];
            bh[f] = *(const bf16x8*)&lds[cur][2][brow + f * 512 + aoff];
            bl[f] = *(const bf16x8*)&lds[cur][3][brow + f * 512 + aoff];
        }
#pragma unroll
        for (int fm = 0; fm < 4; fm++)
#pragma unroll
            for (int fn = 0; fn < 4; fn++) {
                acc[fm][fn] = __builtin_amdgcn_mfma_f32_16x16x32_bf16(ah[fm], bh[fn], acc[fm][fn], 0, 0, 0);
                acc[fm][fn] = __builtin_amdgcn_mfma_f32_16x16x32_bf16(ah[fm], bl[fn], acc[fm][fn], 0, 0, 0);
                acc[fm][fn] = __builtin_amdgcn_mfma_f32_16x16x32_bf16(al[fm], bh[fn], acc[fm][fn], 0, 0, 0);
            }
        __syncthreads();
    }

    // ---- epilogue: C/D layout col = lane&15, row = (lane>>4)*4 + e ----
    const int rb = bm + (w >> 1) * 64;
    const int cb = bn + (w & 1) * 64;
    float bv[4];
#pragma unroll
    for (int fn = 0; fn < 4; fn++) bv[fn] = bias[cb + fn * 16 + (lane & 15)];
#pragma unroll
    for (int fm = 0; fm < 4; fm++)
#pragma unroll
        for (int e = 0; e < 4; e++) {
            int row = rb + fm * 16 + (lane >> 4) * 4 + e;
            float* cp = &C[(size_t)row * N];
#pragma unroll
            for (int fn = 0; fn < 4; fn++)
                cp[cb + fn * 16 + (lane & 15)] = acc[fm][fn][e] + bv[fn];
        }
}

// ---------------------------------------------------------------------------
// Bin assignment + soft aggregation (unchanged from round 2; ~2 us/dispatch).
// ---------------------------------------------------------------------------
__global__ __launch_bounds__(256)
void bin_assign_agg(const float* __restrict__ Kbuf, const float* __restrict__ Vbuf,
                    const float* __restrict__ W_bin, const float* __restrict__ proto,
                    const float* __restrict__ log_tau,
                    float* __restrict__ partials, int B, int S)
{
    const int bh = blockIdx.x;
    const int h  = bh & (N_HEADS - 1);
    const int b  = bh >> 4;
    const int chunk = blockIdx.y;
    const int CH = gridDim.y;
    const int tid = threadIdx.x;

    __shared__ __attribute__((aligned(16))) float Wb[8][64];
    __shared__ __attribute__((aligned(16))) float Prt[8][64];
    __shared__ __attribute__((aligned(16))) float zsm[64][8];
    __shared__ __attribute__((aligned(16))) float Kt[64][68];
    __shared__ __attribute__((aligned(16))) float Vt[64][68];
    __shared__ __attribute__((aligned(16))) float Pt[64][68];

    if (tid < 128) {
        ((f4*)&Wb[0][0])[tid] = ((const f4*)W_bin)[tid];
    } else {
        int t = tid - 128;
        f4 p = ((const f4*)(proto + (size_t)h * N_BINS * D_LAT))[t];
        int n = t >> 1, l4 = (t & 1) * 4;
        Prt[l4 + 0][n] = p[0];
        Prt[l4 + 1][n] = p[1];
        Prt[l4 + 2][n] = p[2];
        Prt[l4 + 3][n] = p[3];
    }
    const float tau   = fmaxf(expf(log_tau[h]), 1e-3f);
    const float scale = 1.0f / (tau + 1e-8f);

    const int row = tid >> 2, sub = tid & 3;
    const int n0 = (tid >> 4) * 4, d0 = (tid & 15) * 4;

    float accK[4][4], accV[4][4], cnt[4];
#pragma unroll
    for (int i = 0; i < 4; i++) {
        cnt[i] = 0.f;
#pragma unroll
        for (int j = 0; j < 4; j++) { accK[i][j] = 0.f; accV[i][j] = 0.f; }
    }

    const int SC = S / CH;
    const int s_base = chunk * SC;

    for (int s0 = 0; s0 < SC; s0 += 64) {
        __syncthreads();
#pragma unroll
        for (int q = 0; q < 4; q++) {
            int f  = tid + 256 * q;
            int sl = f >> 4, dd = (f & 15) * 4;
            size_t gi = ((size_t)(b * S + s_base + s0 + sl)) * D_MODEL + h * D_HEAD + dd;
            *(f4*)&Kt[sl][dd] = *(const f4*)&Kbuf[gi];
            *(f4*)&Vt[sl][dd] = *(const f4*)&Vbuf[gi];
        }
        __syncthreads();

        {
            const int l0 = sub * 2;
            f4 z0 = {0.f, 0.f, 0.f, 0.f}, z1 = {0.f, 0.f, 0.f, 0.f};
#pragma unroll
            for (int d4 = 0; d4 < 16; d4++) {
                f4 kv = *(const f4*)&Kt[row][d4 * 4];
                f4 w0 = *(const f4*)&Wb[l0][d4 * 4];
                f4 w1 = *(const f4*)&Wb[l0 + 1][d4 * 4];
                z0 += kv * w0;
                z1 += kv * w1;
            }
            zsm[row][l0]     = z0[0] + z0[1] + z0[2] + z0[3];
            zsm[row][l0 + 1] = z1[0] + z1[1] + z1[2] + z1[3];
        }
        __syncthreads();

        {
            float zr[8];
#pragma unroll
            for (int l = 0; l < 8; l++) zr[l] = zsm[row][l];
            f4 lg[4];
#pragma unroll
            for (int q = 0; q < 4; q++) lg[q] = (f4){0.f, 0.f, 0.f, 0.f};
#pragma unroll
            for (int l = 0; l < 8; l++) {
                float zv = zr[l];
#pragma unroll
                for (int q = 0; q < 4; q++) {
                    f4 pr = *(const f4*)&Prt[l][sub * 16 + q * 4];
                    lg[q] += zv * pr;
                }
            }
            float mx = -1e30f;
#pragma unroll
            for (int q = 0; q < 4; q++) {
                lg[q] *= scale;
                mx = fmaxf(mx, fmaxf(fmaxf(lg[q][0], lg[q][1]), fmaxf(lg[q][2], lg[q][3])));
            }
            mx = fmaxf(mx, __shfl_xor(mx, 1));
            mx = fmaxf(mx, __shfl_xor(mx, 2));
            float sum = 0.f;
            f4 pv[4];
#pragma unroll
            for (int q = 0; q < 4; q++) {
#pragma unroll
                for (int e = 0; e < 4; e++) {
                    float ev = expf(lg[q][e] - mx);
                    pv[q][e] = ev;
                    sum += ev;
                }
            }
            sum += __shfl_xor(sum, 1);
            sum += __shfl_xor(sum, 2);
            float inv = 1.0f / sum;
#pragma unroll
            for (int q = 0; q < 4; q++) {
                pv[q] *= inv;
                *(f4*)&Pt[row][sub * 16 + q * 4] = pv[q];
            }
        }
        __syncthreads();

#pragma unroll 4
        for (int s = 0; s < 64; s++) {
            f4 pp = *(const f4*)&Pt[s][n0];
            f4 kk = *(const f4*)&Kt[s][d0];
            f4 vv = *(const f4*)&Vt[s][d0];
#pragma unroll
            for (int i = 0; i < 4; i++) {
                float p = pp[i];
#pragma unroll
                for (int j = 0; j < 4; j++) {
                    accK[i][j] += p * kk[j];
                    accV[i][j] += p * vv[j];
                }
            }
            if ((tid & 15) == 0) {
#pragma unroll
                for (int i = 0; i < 4; i++) cnt[i] += pp[i];
            }
        }
    }

    float* base = partials + ((size_t)bh * CH + chunk) * 8256;
#pragma unroll
    for (int i = 0; i < 4; i++) {
#pragma unroll
        for (int j = 0; j < 4; j++) {
            base[(size_t)(n0 + i) * 64 + d0 + j]        = accK[i][j];
            base[4096 + (size_t)(n0 + i) * 64 + d0 + j] = accV[i][j];
        }
        if ((tid & 15) == 0) base[8192 + n0 + i] = cnt[i];
    }
}

// ---------------------------------------------------------------------------
// Reduce partials -> K_binned, V_binned (FAITHFUL to reference broadcast bug:
// feature d divided by counts[d]).
// ---------------------------------------------------------------------------
__global__ __launch_bounds__(256)
void bin_reduce(const float* __restrict__ partials, float* __restrict__ Kb,
                float* __restrict__ Vb, int CH)
{
    const int bh = blockIdx.x;
    const int tid = threadIdx.x;
    __shared__ float inv_cnt[64];
    const float* base = partials + (size_t)bh * CH * 8256;
    if (tid < 64) {
        float c = 0.f;
        for (int ch = 0; ch < CH; ch++) c += base[(size_t)ch * 8256 + 8192 + tid];
        inv_cnt[tid] = 1.0f / (c + 1e-6f);
    }
    __syncthreads();
    for (int idx = tid; idx < 4096; idx += 256) {
        float k = 0.f, v = 0.f;
        for (int ch = 0; ch < CH; ch++) {
            const float* p = base + (size_t)ch * 8256;
            k += p[idx];
            v += p[4096 + idx];
        }
        float ic = inv_cnt[idx & 63];
        Kb[(size_t)bh * 4096 + idx] = k * ic;
        Vb[(size_t)bh * 4096 + idx] = v * ic;
    }
}

// ---------------------------------------------------------------------------
// Bin attention; epilogue now writes ctx directly as bf16 hi/lo splits
// (fuses the ctx split pass for the Wo GEMM).
// ---------------------------------------------------------------------------
__global__ __launch_bounds__(256)
void bin_attention(const float* __restrict__ Qbuf, const float* __restrict__ Kb,
                   const float* __restrict__ Vb,
                   unsigned short* __restrict__ ctx_hi, unsigned short* __restrict__ ctx_lo,
                   int B, int S)
{
    const int bh = blockIdx.x;
    const int h  = bh & (N_HEADS - 1);
    const int b  = bh >> 4;
    const int tid = threadIdx.x;
    const int row = tid >> 2, sub = tid & 3;

    __shared__ __attribute__((aligned(16))) float Kbs[64][68];
    __shared__ __attribute__((aligned(16))) float Vbs[64][68];
    __shared__ __attribute__((aligned(16))) float Qt[64][68];

    const float* kbp = Kb + (size_t)bh * 4096;
    const float* vbp = Vb + (size_t)bh * 4096;
#pragma unroll
    for (int q = 0; q < 4; q++) {
        int f = tid + 256 * q;
        int n = f >> 4, c = (f & 15) * 4;
        *(f4*)&Kbs[n][c] = *(const f4*)&kbp[(size_t)f * 4];
        *(f4*)&Vbs[n][c] = *(const f4*)&vbp[(size_t)f * 4];
    }
    const int s0 = blockIdx.y * 64;
#pragma unroll
    for (int q = 0; q < 4; q++) {
        int f = tid + 256 * q;
        int sl = f >> 4, dd = (f & 15) * 4;
        size_t gi = ((size_t)(b * S + s0 + sl)) * D_MODEL + h * D_HEAD + dd;
        *(f4*)&Qt[sl][dd] = *(const f4*)&Qbuf[gi];
    }
    __syncthreads();

    f4 wa[16];
#pragma unroll
    for (int j = 0; j < 16; j++) wa[j] = (f4){0.f, 0.f, 0.f, 0.f};
    for (int d4 = 0; d4 < 16; d4++) {
        f4 qv = *(const f4*)&Qt[row][d4 * 4];
#pragma unroll
        for (int j = 0; j < 16; j++) {
            f4 kk = *(const f4*)&Kbs[4 * j + sub][d4 * 4];
            wa[j] += qv * kk;
        }
    }
    float wv[16];
    float mx = -1e30f;
#pragma unroll
    for (int j = 0; j < 16; j++) {
        wv[j] = (wa[j][0] + wa[j][1] + wa[j][2] + wa[j][3]) * 0.125f;
        mx = fmaxf(mx, wv[j]);
    }
    mx = fmaxf(mx, __shfl_xor(mx, 1));
    mx = fmaxf(mx, __shfl_xor(mx, 2));
    float sum = 0.f;
#pragma unroll
    for (int j = 0; j < 16; j++) {
        wv[j] = expf(wv[j] - mx);
        sum += wv[j];
    }
    sum += __shfl_xor(sum, 1);
    sum += __shfl_xor(sum, 2);
    float inv = 1.0f / sum;

#pragma unroll
    for (int j = 0; j < 16; j++) Qt[row][4 * j + sub] = wv[j] * inv;

    f4 ca[16];
#pragma unroll
    for (int q = 0; q < 16; q++) ca[q] = (f4){0.f, 0.f, 0.f, 0.f};
    for (int j = 0; j < 16; j++) {
        float wn = Qt[row][4 * j + sub];
#pragma unroll
        for (int d4 = 0; d4 < 16; d4++) {
            f4 vv = *(const f4*)&Vbs[4 * j + sub][d4 * 4];
            ca[d4] += wn * vv;
        }
    }

    const bool low2 = (sub & 2) == 0;
    f4 halfv[8];
#pragma unroll
    for (int q = 0; q < 8; q++) {
#pragma unroll
        for (int e = 0; e < 4; e++) {
            float send = low2 ? ca[8 + q][e] : ca[q][e];
            float recv = __shfl_xor(send, 2);
            float mine = low2 ? ca[q][e] : ca[8 + q][e];
            halfv[q][e] = mine + recv;
        }
    }
    const bool low1 = (sub & 1) == 0;
    f4 quar[4];
#pragma unroll
    for (int q = 0; q < 4; q++) {
#pragma unroll
        for (int e = 0; e < 4; e++) {
            float send = low1 ? halfv[4 + q][e] : halfv[q][e];
            float recv = __shfl_xor(send, 1);
            float mine = low1 ? halfv[q][e] : halfv[4 + q][e];
            quar[q][e] = mine + recv;
        }
    }

    size_t go = ((size_t)(b * S + s0 + row)) * D_MODEL + h * D_HEAD + sub * 16;
#pragma unroll
    for (int q = 0; q < 4; q++) {
        unsigned short hs[4], ls[4];
#pragma unroll
        for (int e = 0; e < 4; e++) {
            float v = quar[q][e];
            hs[e] = bf16_rtne(v);
            ls[e] = bf16_rtne(v - bf16_to_f32(hs[e]));
        }
        u32x2 hp = { (unsigned int)hs[0] | ((unsigned int)hs[1] << 16),
                     (unsigned int)hs[2] | ((unsigned int)hs[3] << 16) };
        u32x2 lp = { (unsigned int)ls[0] | ((unsigned int)ls[1] << 16),
                     (unsigned int)ls[2] | ((unsigned int)ls[3] << 16) };
        *(u32x2*)&ctx_hi[go + q * 4] = hp;
        *(u32x2*)&ctx_lo[go + q * 4] = lp;
    }
}

// ---------------------------------------------------------------------------
extern "C" void kernel_launch(void* const* d_in, const int* in_sizes, int n_in,
                              void* d_out, int out_size, void* d_ws, size_t ws_size,
                              hipStream_t stream)
{
    (void)n_in; (void)out_size; (void)ws_size;
    const float* x       = (const float*)d_in[0];
    const float* Wq      = (const float*)d_in[1];
    const float* bq      = (const float*)d_in[2];
    const float* Wk      = (const float*)d_in[3];
    const float* bk      = (const float*)d_in[4];
    const float* Wv      = (const float*)d_in[5];
    const float* bv      = (const float*)d_in[6];
    const float* Wo      = (const float*)d_in[7];
    const float* bo      = (const float*)d_in[8];
    const float* W_bin   = (const float*)d_in[9];
    const float* proto   = (const float*)d_in[10];
    const float* log_tau = (const float*)d_in[11];
    float* out = (float*)d_out;

    const int M  = in_sizes[0] / D_MODEL;   // B*S = 16384
    const int S  = 4096;
    const int B  = M / S;                   // 4
    const int BH = B * N_HEADS;             // 64
    const int CH = 8;

    const size_t MB = (size_t)1 << 20;
    char* wsb = (char*)d_ws;
    float*          R1   = (float*)wsb;                        // 64 MB: K, then Q
    float*          R2   = (float*)(wsb + 64  * MB);           // 64 MB: V
    unsigned short* XShi = (unsigned short*)(wsb + 128 * MB);  // 32 MB: x_hi -> ctx_hi
    unsigned short* XSlo = (unsigned short*)(wsb + 160 * MB);  // 32 MB: x_lo -> ctx_lo
    unsigned short* Whi  = (unsigned short*)(wsb + 192 * MB);  //  2 MB (reused per weight)
    unsigned short* Wlo  = (unsigned short*)(wsb + 194 * MB);  //  2 MB
    float*          part = (float*)(wsb + 196 * MB);           // ~16.2 MB
    float*          Kb   = part + (size_t)BH * CH * 8256;
    float*          Vb   = Kb + (size_t)BH * 4096;

    const int n8x = (M * D_MODEL) / 8;            // 2,097,152
    const int n8w = (D_MODEL * D_MODEL) / 8;      // 131,072
    dim3 gg(M / 128, D_MODEL / 128);              // (128, 8): same-A-panel blocks share XCD

    split_bf16x2<<<n8x / 256, 256, 0, stream>>>(x, XShi, XSlo, n8x);

    split_bf16x2<<<n8w / 256, 256, 0, stream>>>(Wk, Whi, Wlo, n8w);
    gemm_bf16x2_nt<<<gg, 256, 0, stream>>>(XShi, XSlo, Whi, Wlo, bk, R1, M, D_MODEL, D_MODEL);

    split_bf16x2<<<n8w / 256, 256, 0, stream>>>(Wv, Whi, Wlo, n8w);
    gemm_bf16x2_nt<<<gg, 256, 0, stream>>>(XShi, XSlo, Whi, Wlo, bv, R2, M, D_MODEL, D_MODEL);

    bin_assign_agg<<<dim3(BH, CH), 256, 0, stream>>>(R1, R2, W_bin, proto,
                                                     log_tau, part, B, S);
    bin_reduce<<<BH, 256, 0, stream>>>(part, Kb, Vb, CH);

    split_bf16x2<<<n8w / 256, 256, 0, stream>>>(Wq, Whi, Wlo, n8w);
    gemm_bf16x2_nt<<<gg, 256, 0, stream>>>(XShi, XSlo, Whi, Wlo, bq, R1, M, D_MODEL, D_MODEL);

    // writes ctx splits into XShi/XSlo (x is dead after the Q projection)
    bin_attention<<<dim3(BH, S / 64), 256, 0, stream>>>(R1, Kb, Vb, XShi, XSlo, B, S);

    split_bf16x2<<<n8w / 256, 256, 0, stream>>>(Wo, Whi, Wlo, n8w);
    gemm_bf16x2_nt<<<gg, 256, 0, stream>>>(XShi, XSlo, Whi, Wlo, bo, out, M, D_MODEL, D_MODEL);
}

// Round 4
// 572.185 us; speedup vs baseline: 2.9910x; 1.0545x over previous
//
#include <hip/hip_runtime.h>
#include <math.h>

typedef float f4 __attribute__((ext_vector_type(4)));
typedef float f32x4 __attribute__((ext_vector_type(4)));
typedef short bf16x8 __attribute__((ext_vector_type(8)));
typedef unsigned int u32x4 __attribute__((ext_vector_type(4)));
typedef unsigned int u32x2 __attribute__((ext_vector_type(2)));
typedef unsigned short u16;

#define D_MODEL 1024
#define N_HEADS 16
#define D_HEAD  64
#define N_BINS  64
#define D_LAT   8

// ---------------------------------------------------------------------------
// bf16 split helpers (RTNE)
// ---------------------------------------------------------------------------
__device__ __forceinline__ unsigned short bf16_rtne(float f) {
    unsigned int u = __builtin_bit_cast(unsigned int, f);
    u += 0x7FFFu + ((u >> 16) & 1u);
    return (unsigned short)(u >> 16);
}
__device__ __forceinline__ float bf16_to_f32(unsigned short h) {
    unsigned int u = ((unsigned int)h) << 16;
    return __builtin_bit_cast(float, u);
}

// fp32 -> (hi, lo) bf16 buffers, 8 elems/thread
__global__ __launch_bounds__(256)
void split_bf16x2(const float* __restrict__ in, unsigned short* __restrict__ hi,
                  unsigned short* __restrict__ lo, int n8)
{
    int i = blockIdx.x * 256 + threadIdx.x;
    if (i >= n8) return;
    const f4* inp = (const f4*)in;
    f4 a = inp[2 * i];
    f4 b = inp[2 * i + 1];
    unsigned short hs[8], ls[8];
#pragma unroll
    for (int j = 0; j < 8; j++) {
        float v = (j < 4) ? a[j] : b[j - 4];
        unsigned short h = bf16_rtne(v);
        hs[j] = h;
        ls[j] = bf16_rtne(v - bf16_to_f32(h));
    }
    u32x4 ho, lv;
#pragma unroll
    for (int j = 0; j < 4; j++) {
        ho[j] = (unsigned int)hs[2 * j] | ((unsigned int)hs[2 * j + 1] << 16);
        lv[j] = (unsigned int)ls[2 * j] | ((unsigned int)ls[2 * j + 1] << 16);
    }
    ((u32x4*)hi)[i] = ho;
    ((u32x4*)lo)[i] = lv;
}

// ---------------------------------------------------------------------------
// Split-bf16 MFMA GEMM (NT): C[M,N] = (Ahi+Alo)[M,K] * (Whi+Wlo)[N,K]^T + bias
// acc = Ahi*Whi + Ahi*Wlo + Alo*Whi (fp32 MFMA accumulate).
// SPLIT=false: write fp32 C.  SPLIT=true: write bf16 hi/lo C (for Q).
// ---------------------------------------------------------------------------
__device__ __forceinline__ void glds16(const unsigned short* g, unsigned short* l) {
    __builtin_amdgcn_global_load_lds((const __attribute__((address_space(1))) void*)g,
                                     (__attribute__((address_space(3))) void*)l,
                                     16, 0, 0);
}

template<bool SPLIT>
__global__ __launch_bounds__(256)
void gemm_bf16x2_nt(const unsigned short* __restrict__ Ahi, const unsigned short* __restrict__ Alo,
                    const unsigned short* __restrict__ Bhi, const unsigned short* __restrict__ Blo,
                    const float* __restrict__ bias, float* __restrict__ C,
                    unsigned short* __restrict__ Chi, unsigned short* __restrict__ Clo,
                    int M, int N, int K)
{
    __shared__ unsigned short lds[2][4][4096];

    const int tid  = threadIdx.x;
    const int lane = tid & 63;
    const int w    = tid >> 6;
    const int bm   = blockIdx.x * 128;
    const int bn   = blockIdx.y * 128;

    const int schunk = (lane & 3) ^ ((lane >> 2) & 3);
    size_t gA[2], gB[2];
    int    seg[2];
#pragma unroll
    for (int i = 0; i < 2; i++) {
        int s = i * 4 + w;
        int r = s * 16 + (lane >> 2);
        gA[i]  = (size_t)(bm + r) * K + schunk * 8;
        gB[i]  = (size_t)(bn + r) * K + schunk * 8;
        seg[i] = s * 512;
    }

    const int aoff = (lane & 15) * 32 + (((lane >> 4) ^ (lane & 3)) * 8);
    const int arow = (w >> 1) * 2048;
    const int brow = (w & 1) * 2048;

    f32x4 acc[4][4];
#pragma unroll
    for (int i = 0; i < 4; i++)
#pragma unroll
        for (int j = 0; j < 4; j++) acc[i][j] = (f32x4){0.f, 0.f, 0.f, 0.f};

    auto stage = [&](int b, int kt) {
#pragma unroll
        for (int i = 0; i < 2; i++) {
            glds16(Ahi + gA[i] + kt, &lds[b][0][seg[i]]);
            glds16(Alo + gA[i] + kt, &lds[b][1][seg[i]]);
            glds16(Bhi + gB[i] + kt, &lds[b][2][seg[i]]);
            glds16(Blo + gB[i] + kt, &lds[b][3][seg[i]]);
        }
    };

    stage(0, 0);
    __syncthreads();

    const int nt = K / 32;
    for (int t = 0; t < nt; t++) {
        const int cur = t & 1;
        if (t + 1 < nt) stage(cur ^ 1, (t + 1) * 32);

        bf16x8 ah[4], al[4], bh[4], bl[4];
#pragma unroll
        for (int f = 0; f < 4; f++) {
            ah[f] = *(const bf16x8*)&lds[cur][0][arow + f * 512 + aoff];
            al[f] = *(const bf16x8*)&lds[cur][1][arow + f * 512 + aoff];
            bh[f] = *(const bf16x8*)&lds[cur][2][brow + f * 512 + aoff];
            bl[f] = *(const bf16x8*)&lds[cur][3][brow + f * 512 + aoff];
        }
#pragma unroll
        for (int fm = 0; fm < 4; fm++)
#pragma unroll
            for (int fn = 0; fn < 4; fn++) {
                acc[fm][fn] = __builtin_amdgcn_mfma_f32_16x16x32_bf16(ah[fm], bh[fn], acc[fm][fn], 0, 0, 0);
                acc[fm][fn] = __builtin_amdgcn_mfma_f32_16x16x32_bf16(ah[fm], bl[fn], acc[fm][fn], 0, 0, 0);
                acc[fm][fn] = __builtin_amdgcn_mfma_f32_16x16x32_bf16(al[fm], bh[fn], acc[fm][fn], 0, 0, 0);
            }
        __syncthreads();
    }

    const int rb = bm + (w >> 1) * 64;
    const int cb = bn + (w & 1) * 64;
    float bv[4];
#pragma unroll
    for (int fn = 0; fn < 4; fn++) bv[fn] = bias[cb + fn * 16 + (lane & 15)];
#pragma unroll
    for (int fm = 0; fm < 4; fm++)
#pragma unroll
        for (int e = 0; e < 4; e++) {
            size_t row = (size_t)(rb + fm * 16 + (lane >> 4) * 4 + e);
            if constexpr (SPLIT) {
#pragma unroll
                for (int fn = 0; fn < 4; fn++) {
                    float v = acc[fm][fn][e] + bv[fn];
                    unsigned short h = bf16_rtne(v);
                    Chi[row * N + cb + fn * 16 + (lane & 15)] = h;
                    Clo[row * N + cb + fn * 16 + (lane & 15)] = bf16_rtne(v - bf16_to_f32(h));
                }
            } else {
                float* cp = &C[row * N];
#pragma unroll
                for (int fn = 0; fn < 4; fn++)
                    cp[cb + fn * 16 + (lane & 15)] = acc[fm][fn][e] + bv[fn];
            }
        }
}

// ---------------------------------------------------------------------------
// Bin assignment + soft aggregation (unchanged).
// ---------------------------------------------------------------------------
__global__ __launch_bounds__(256)
void bin_assign_agg(const float* __restrict__ Kbuf, const float* __restrict__ Vbuf,
                    const float* __restrict__ W_bin, const float* __restrict__ proto,
                    const float* __restrict__ log_tau,
                    float* __restrict__ partials, int B, int S)
{
    const int bh = blockIdx.x;
    const int h  = bh & (N_HEADS - 1);
    const int b  = bh >> 4;
    const int chunk = blockIdx.y;
    const int CH = gridDim.y;
    const int tid = threadIdx.x;

    __shared__ __attribute__((aligned(16))) float Wb[8][64];
    __shared__ __attribute__((aligned(16))) float Prt[8][64];
    __shared__ __attribute__((aligned(16))) float zsm[64][8];
    __shared__ __attribute__((aligned(16))) float Kt[64][68];
    __shared__ __attribute__((aligned(16))) float Vt[64][68];
    __shared__ __attribute__((aligned(16))) float Pt[64][68];

    if (tid < 128) {
        ((f4*)&Wb[0][0])[tid] = ((const f4*)W_bin)[tid];
    } else {
        int t = tid - 128;
        f4 p = ((const f4*)(proto + (size_t)h * N_BINS * D_LAT))[t];
        int n = t >> 1, l4 = (t & 1) * 4;
        Prt[l4 + 0][n] = p[0];
        Prt[l4 + 1][n] = p[1];
        Prt[l4 + 2][n] = p[2];
        Prt[l4 + 3][n] = p[3];
    }
    const float tau   = fmaxf(expf(log_tau[h]), 1e-3f);
    const float scale = 1.0f / (tau + 1e-8f);

    const int row = tid >> 2, sub = tid & 3;
    const int n0 = (tid >> 4) * 4, d0 = (tid & 15) * 4;

    float accK[4][4], accV[4][4], cnt[4];
#pragma unroll
    for (int i = 0; i < 4; i++) {
        cnt[i] = 0.f;
#pragma unroll
        for (int j = 0; j < 4; j++) { accK[i][j] = 0.f; accV[i][j] = 0.f; }
    }

    const int SC = S / CH;
    const int s_base = chunk * SC;

    for (int s0 = 0; s0 < SC; s0 += 64) {
        __syncthreads();
#pragma unroll
        for (int q = 0; q < 4; q++) {
            int f  = tid + 256 * q;
            int sl = f >> 4, dd = (f & 15) * 4;
            size_t gi = ((size_t)(b * S + s_base + s0 + sl)) * D_MODEL + h * D_HEAD + dd;
            *(f4*)&Kt[sl][dd] = *(const f4*)&Kbuf[gi];
            *(f4*)&Vt[sl][dd] = *(const f4*)&Vbuf[gi];
        }
        __syncthreads();

        {
            const int l0 = sub * 2;
            f4 z0 = {0.f, 0.f, 0.f, 0.f}, z1 = {0.f, 0.f, 0.f, 0.f};
#pragma unroll
            for (int d4 = 0; d4 < 16; d4++) {
                f4 kv = *(const f4*)&Kt[row][d4 * 4];
                f4 w0 = *(const f4*)&Wb[l0][d4 * 4];
                f4 w1 = *(const f4*)&Wb[l0 + 1][d4 * 4];
                z0 += kv * w0;
                z1 += kv * w1;
            }
            zsm[row][l0]     = z0[0] + z0[1] + z0[2] + z0[3];
            zsm[row][l0 + 1] = z1[0] + z1[1] + z1[2] + z1[3];
        }
        __syncthreads();

        {
            float zr[8];
#pragma unroll
            for (int l = 0; l < 8; l++) zr[l] = zsm[row][l];
            f4 lg[4];
#pragma unroll
            for (int q = 0; q < 4; q++) lg[q] = (f4){0.f, 0.f, 0.f, 0.f};
#pragma unroll
            for (int l = 0; l < 8; l++) {
                float zv = zr[l];
#pragma unroll
                for (int q = 0; q < 4; q++) {
                    f4 pr = *(const f4*)&Prt[l][sub * 16 + q * 4];
                    lg[q] += zv * pr;
                }
            }
            float mx = -1e30f;
#pragma unroll
            for (int q = 0; q < 4; q++) {
                lg[q] *= scale;
                mx = fmaxf(mx, fmaxf(fmaxf(lg[q][0], lg[q][1]), fmaxf(lg[q][2], lg[q][3])));
            }
            mx = fmaxf(mx, __shfl_xor(mx, 1));
            mx = fmaxf(mx, __shfl_xor(mx, 2));
            float sum = 0.f;
            f4 pv[4];
#pragma unroll
            for (int q = 0; q < 4; q++) {
#pragma unroll
                for (int e = 0; e < 4; e++) {
                    float ev = expf(lg[q][e] - mx);
                    pv[q][e] = ev;
                    sum += ev;
                }
            }
            sum += __shfl_xor(sum, 1);
            sum += __shfl_xor(sum, 2);
            float inv = 1.0f / sum;
#pragma unroll
            for (int q = 0; q < 4; q++) {
                pv[q] *= inv;
                *(f4*)&Pt[row][sub * 16 + q * 4] = pv[q];
            }
        }
        __syncthreads();

#pragma unroll 4
        for (int s = 0; s < 64; s++) {
            f4 pp = *(const f4*)&Pt[s][n0];
            f4 kk = *(const f4*)&Kt[s][d0];
            f4 vv = *(const f4*)&Vt[s][d0];
#pragma unroll
            for (int i = 0; i < 4; i++) {
                float p = pp[i];
#pragma unroll
                for (int j = 0; j < 4; j++) {
                    accK[i][j] += p * kk[j];
                    accV[i][j] += p * vv[j];
                }
            }
            if ((tid & 15) == 0) {
#pragma unroll
                for (int i = 0; i < 4; i++) cnt[i] += pp[i];
            }
        }
    }

    float* base = partials + ((size_t)bh * CH + chunk) * 8256;
#pragma unroll
    for (int i = 0; i < 4; i++) {
#pragma unroll
        for (int j = 0; j < 4; j++) {
            base[(size_t)(n0 + i) * 64 + d0 + j]        = accK[i][j];
            base[4096 + (size_t)(n0 + i) * 64 + d0 + j] = accV[i][j];
        }
        if ((tid & 15) == 0) base[8192 + n0 + i] = cnt[i];
    }
}

// ---------------------------------------------------------------------------
// Reduce partials -> bf16 hi/lo K_binned [bh][n][d] and V_binned^T [bh][d][n].
// FAITHFUL to reference broadcast bug: feature d divided by counts[d].
// ---------------------------------------------------------------------------
__global__ __launch_bounds__(256)
void bin_reduce(const float* __restrict__ partials,
                u16* __restrict__ Kbh, u16* __restrict__ Kbl,
                u16* __restrict__ Vth, u16* __restrict__ Vtl, int CH)
{
    const int bh = blockIdx.x;
    const int tid = threadIdx.x;
    __shared__ float inv_cnt[64];
    const float* base = partials + (size_t)bh * CH * 8256;
    if (tid < 64) {
        float c = 0.f;
        for (int ch = 0; ch < CH; ch++) c += base[(size_t)ch * 8256 + 8192 + tid];
        inv_cnt[tid] = 1.0f / (c + 1e-6f);
    }
    __syncthreads();
    for (int idx = tid; idx < 4096; idx += 256) {
        float k = 0.f, v = 0.f;
        for (int ch = 0; ch < CH; ch++) {
            const float* p = base + (size_t)ch * 8256;
            k += p[idx];
            v += p[4096 + idx];
        }
        float ic = inv_cnt[idx & 63];   // divide by count of FEATURE index d
        k *= ic;
        v *= ic;
        int n = idx >> 6, d = idx & 63;
        u16 kh = bf16_rtne(k);
        Kbh[(size_t)bh * 4096 + idx] = kh;
        Kbl[(size_t)bh * 4096 + idx] = bf16_rtne(k - bf16_to_f32(kh));
        u16 vh = bf16_rtne(v);
        size_t ti = (size_t)bh * 4096 + (size_t)d * 64 + n;   // transposed
        Vth[ti] = vh;
        Vtl[ti] = bf16_rtne(v - bf16_to_f32(vh));
    }
}

// ---------------------------------------------------------------------------
// Bin attention via bf16x2 MFMA.
// grid = (BH, S/256); 4 waves/block, each wave owns 64 q-rows.
// QK^T: A=Q frags from global (bf16 hi/lo), B=K_binned frags (n-major).
// Softmax in MFMA C-layout (shfl_xor over lane&15 group).
// P (hi|lo packed u32) -> LDS [64][68] -> A-frags for PV; B=V_binned^T frags.
// Epilogue writes ctx as bf16 hi/lo for the Wo GEMM.
// ---------------------------------------------------------------------------
__global__ __launch_bounds__(256)
void bin_attn_mfma(const u16* __restrict__ Qhi, const u16* __restrict__ Qlo,
                   const u16* __restrict__ Kbh, const u16* __restrict__ Kbl,
                   const u16* __restrict__ Vth, const u16* __restrict__ Vtl,
                   u16* __restrict__ ctx_hi, u16* __restrict__ ctx_lo,
                   int B, int S)
{
    __shared__ unsigned int P32[4][64][68];   // hi|lo packed, pad 68 (2-way max)

    const int bh = blockIdx.x;
    const int h  = bh & (N_HEADS - 1);
    const int b  = bh >> 4;
    const int tid = threadIdx.x;
    const int l  = tid & 63;
    const int w  = tid >> 6;
    const int s0 = blockIdx.y * 256 + w * 64;

    const int lr = l & 15;    // fragment row / col index
    const int lc = l >> 4;    // fragment k-chunk / row-subgroup

    const size_t qoff  = ((size_t)(b * S + s0 + lr)) * D_MODEL + h * D_HEAD + lc * 8;
    const size_t kboff = (size_t)bh * 4096 + (size_t)lr * 64 + lc * 8;

    // ---------------- QK^T ----------------
    f32x4 acc[4][4];
#pragma unroll
    for (int i = 0; i < 4; i++)
#pragma unroll
        for (int j = 0; j < 4; j++) acc[i][j] = (f32x4){0.f, 0.f, 0.f, 0.f};

#pragma unroll
    for (int ks = 0; ks < 2; ks++) {
        bf16x8 qh[4], ql[4], kh[4], kl[4];
#pragma unroll
        for (int f = 0; f < 4; f++) {
            qh[f] = *(const bf16x8*)(Qhi + qoff + f * 16 * D_MODEL + ks * 32);
            ql[f] = *(const bf16x8*)(Qlo + qoff + f * 16 * D_MODEL + ks * 32);
            kh[f] = *(const bf16x8*)(Kbh + kboff + f * 1024 + ks * 32);
            kl[f] = *(const bf16x8*)(Kbl + kboff + f * 1024 + ks * 32);
        }
#pragma unroll
        for (int fm = 0; fm < 4; fm++)
#pragma unroll
            for (int fn = 0; fn < 4; fn++) {
                acc[fm][fn] = __builtin_amdgcn_mfma_f32_16x16x32_bf16(qh[fm], kh[fn], acc[fm][fn], 0, 0, 0);
                acc[fm][fn] = __builtin_amdgcn_mfma_f32_16x16x32_bf16(qh[fm], kl[fn], acc[fm][fn], 0, 0, 0);
                acc[fm][fn] = __builtin_amdgcn_mfma_f32_16x16x32_bf16(ql[fm], kh[fn], acc[fm][fn], 0, 0, 0);
            }
    }

    // ------------- softmax over 64 bins, per q-row -------------
    // acc[fm][fn][e] = S[q = fm*16 + lc*4 + e][n = fn*16 + lr]
#pragma unroll
    for (int fm = 0; fm < 4; fm++) {
#pragma unroll
        for (int e = 0; e < 4; e++) {
            float v0 = acc[fm][0][e] * 0.125f;
            float v1 = acc[fm][1][e] * 0.125f;
            float v2 = acc[fm][2][e] * 0.125f;
            float v3 = acc[fm][3][e] * 0.125f;
            float mx = fmaxf(fmaxf(v0, v1), fmaxf(v2, v3));
            mx = fmaxf(mx, __shfl_xor(mx, 1));
            mx = fmaxf(mx, __shfl_xor(mx, 2));
            mx = fmaxf(mx, __shfl_xor(mx, 4));
            mx = fmaxf(mx, __shfl_xor(mx, 8));
            float e0 = expf(v0 - mx), e1 = expf(v1 - mx);
            float e2 = expf(v2 - mx), e3 = expf(v3 - mx);
            float sum = e0 + e1 + e2 + e3;
            sum += __shfl_xor(sum, 1);
            sum += __shfl_xor(sum, 2);
            sum += __shfl_xor(sum, 4);
            sum += __shfl_xor(sum, 8);
            float inv = 1.0f / sum;
            float pv[4] = {e0 * inv, e1 * inv, e2 * inv, e3 * inv};
            int row = fm * 16 + lc * 4 + e;
#pragma unroll
            for (int fn = 0; fn < 4; fn++) {
                u16 ph = bf16_rtne(pv[fn]);
                u16 pl = bf16_rtne(pv[fn] - bf16_to_f32(ph));
                P32[w][row][fn * 16 + lr] = (unsigned int)ph | ((unsigned int)pl << 16);
            }
        }
    }
    // only intra-wave LDS dependency (each wave owns P32[w]) — no barrier needed

    // ---------------- PV ----------------
    f32x4 acc2[4][4];
#pragma unroll
    for (int i = 0; i < 4; i++)
#pragma unroll
        for (int j = 0; j < 4; j++) acc2[i][j] = (f32x4){0.f, 0.f, 0.f, 0.f};

#pragma unroll
    for (int ks = 0; ks < 2; ks++) {
        bf16x8 vh[4], vl[4];
#pragma unroll
        for (int f = 0; f < 4; f++) {
            vh[f] = *(const bf16x8*)(Vth + kboff + f * 1024 + ks * 32);
            vl[f] = *(const bf16x8*)(Vtl + kboff + f * 1024 + ks * 32);
        }
        bf16x8 ph[4], pl[4];
#pragma unroll
        for (int fm = 0; fm < 4; fm++) {
            const unsigned int* pr = &P32[w][fm * 16 + lr][ks * 32 + lc * 8];
            u32x4 r0 = *(const u32x4*)pr;
            u32x4 r1 = *(const u32x4*)(pr + 4);
            u32x4 hv, lv;
            hv[0] = (r0[0] & 0xffffu) | (r0[1] << 16);
            lv[0] = (r0[0] >> 16)     | (r0[1] & 0xffff0000u);
            hv[1] = (r0[2] & 0xffffu) | (r0[3] << 16);
            lv[1] = (r0[2] >> 16)     | (r0[3] & 0xffff0000u);
            hv[2] = (r1[0] & 0xffffu) | (r1[1] << 16);
            lv[2] = (r1[0] >> 16)     | (r1[1] & 0xffff0000u);
            hv[3] = (r1[2] & 0xffffu) | (r1[3] << 16);
            lv[3] = (r1[2] >> 16)     | (r1[3] & 0xffff0000u);
            ph[fm] = __builtin_bit_cast(bf16x8, hv);
            pl[fm] = __builtin_bit_cast(bf16x8, lv);
        }
#pragma unroll
        for (int fm = 0; fm < 4; fm++)
#pragma unroll
            for (int fn = 0; fn < 4; fn++) {
                acc2[fm][fn] = __builtin_amdgcn_mfma_f32_16x16x32_bf16(ph[fm], vh[fn], acc2[fm][fn], 0, 0, 0);
                acc2[fm][fn] = __builtin_amdgcn_mfma_f32_16x16x32_bf16(ph[fm], vl[fn], acc2[fm][fn], 0, 0, 0);
                acc2[fm][fn] = __builtin_amdgcn_mfma_f32_16x16x32_bf16(pl[fm], vh[fn], acc2[fm][fn], 0, 0, 0);
            }
    }

    // ------------- epilogue: split ctx to bf16 hi/lo -------------
    // acc2[fm][fn][e] = ctx[q = fm*16 + lc*4 + e][d = fn*16 + lr]
    const size_t gbase = ((size_t)(b * S + s0 + lc * 4)) * D_MODEL + h * D_HEAD + lr;
#pragma unroll
    for (int fm = 0; fm < 4; fm++)
#pragma unroll
        for (int e = 0; e < 4; e++) {
            size_t ro = gbase + ((size_t)(fm * 16 + e)) * D_MODEL;
#pragma unroll
            for (int fn = 0; fn < 4; fn++) {
                float v = acc2[fm][fn][e];
                u16 hv = bf16_rtne(v);
                ctx_hi[ro + fn * 16] = hv;
                ctx_lo[ro + fn * 16] = bf16_rtne(v - bf16_to_f32(hv));
            }
        }
}

// ---------------------------------------------------------------------------
extern "C" void kernel_launch(void* const* d_in, const int* in_sizes, int n_in,
                              void* d_out, int out_size, void* d_ws, size_t ws_size,
                              hipStream_t stream)
{
    (void)n_in; (void)out_size; (void)ws_size;
    const float* x       = (const float*)d_in[0];
    const float* Wq      = (const float*)d_in[1];
    const float* bq      = (const float*)d_in[2];
    const float* Wk      = (const float*)d_in[3];
    const float* bk      = (const float*)d_in[4];
    const float* Wv      = (const float*)d_in[5];
    const float* bv      = (const float*)d_in[6];
    const float* Wo      = (const float*)d_in[7];
    const float* bo      = (const float*)d_in[8];
    const float* W_bin   = (const float*)d_in[9];
    const float* proto   = (const float*)d_in[10];
    const float* log_tau = (const float*)d_in[11];
    float* out = (float*)d_out;

    const int M  = in_sizes[0] / D_MODEL;   // B*S = 16384
    const int S  = 4096;
    const int B  = M / S;                   // 4
    const int BH = B * N_HEADS;             // 64
    const int CH = 8;

    const size_t MB = (size_t)1 << 20;
    char* wsb = (char*)d_ws;
    float*          R1   = (float*)wsb;                        // 64 MB: K fp32, later Q hi/lo
    float*          R2   = (float*)(wsb + 64  * MB);           // 64 MB: V fp32
    unsigned short* XShi = (unsigned short*)(wsb + 128 * MB);  // 32 MB: x_hi -> ctx_hi
    unsigned short* XSlo = (unsigned short*)(wsb + 160 * MB);  // 32 MB: x_lo -> ctx_lo
    unsigned short* Whi  = (unsigned short*)(wsb + 192 * MB);  //  2 MB (reused per weight)
    unsigned short* Wlo  = (unsigned short*)(wsb + 194 * MB);  //  2 MB
    float*          part = (float*)(wsb + 196 * MB);           // ~16.2 MB
    u16*            Kbh  = (u16*)(wsb + 213 * MB);             // 512 KB each
    u16*            Kbl  = Kbh + (size_t)BH * 4096;
    u16*            Vth  = Kbl + (size_t)BH * 4096;
    u16*            Vtl  = Vth + (size_t)BH * 4096;

    u16* Qhi = (u16*)R1;                       // Q hi/lo overlay R1 (K fp32 dead)
    u16* Qlo = Qhi + (size_t)M * D_MODEL;

    const int n8x = (M * D_MODEL) / 8;
    const int n8w = (D_MODEL * D_MODEL) / 8;
    dim3 gg(M / 128, D_MODEL / 128);

    split_bf16x2<<<n8x / 256, 256, 0, stream>>>(x, XShi, XSlo, n8x);

    split_bf16x2<<<n8w / 256, 256, 0, stream>>>(Wk, Whi, Wlo, n8w);
    gemm_bf16x2_nt<false><<<gg, 256, 0, stream>>>(XShi, XSlo, Whi, Wlo, bk, R1,
                                                  nullptr, nullptr, M, D_MODEL, D_MODEL);

    split_bf16x2<<<n8w / 256, 256, 0, stream>>>(Wv, Whi, Wlo, n8w);
    gemm_bf16x2_nt<false><<<gg, 256, 0, stream>>>(XShi, XSlo, Whi, Wlo, bv, R2,
                                                  nullptr, nullptr, M, D_MODEL, D_MODEL);

    bin_assign_agg<<<dim3(BH, CH), 256, 0, stream>>>(R1, R2, W_bin, proto,
                                                     log_tau, part, B, S);
    bin_reduce<<<BH, 256, 0, stream>>>(part, Kbh, Kbl, Vth, Vtl, CH);

    // Q projection writes bf16 hi/lo directly (R1's fp32 K is consumed above)
    split_bf16x2<<<n8w / 256, 256, 0, stream>>>(Wq, Whi, Wlo, n8w);
    gemm_bf16x2_nt<true><<<gg, 256, 0, stream>>>(XShi, XSlo, Whi, Wlo, bq, nullptr,
                                                 Qhi, Qlo, M, D_MODEL, D_MODEL);

    // ctx hi/lo overwrite XShi/XSlo (x splits dead after Q GEMM)
    bin_attn_mfma<<<dim3(BH, S / 256), 256, 0, stream>>>(Qhi, Qlo, Kbh, Kbl, Vth, Vtl,
                                                         XShi, XSlo, B, S);

    split_bf16x2<<<n8w / 256, 256, 0, stream>>>(Wo, Whi, Wlo, n8w);
    gemm_bf16x2_nt<false><<<gg, 256, 0, stream>>>(XShi, XSlo, Whi, Wlo, bo, out,
                                                  nullptr, nullptr, M, D_MODEL, D_MODEL);
}

// Round 5
// 512.943 us; speedup vs baseline: 3.3365x; 1.1155x over previous
//
#include <hip/hip_runtime.h>
#include <math.h>

typedef float f4 __attribute__((ext_vector_type(4)));
typedef float f32x4 __attribute__((ext_vector_type(4)));
typedef short bf16x8 __attribute__((ext_vector_type(8)));
typedef unsigned int u32x4 __attribute__((ext_vector_type(4)));
typedef unsigned int u32x2 __attribute__((ext_vector_type(2)));
typedef unsigned short u16;
typedef unsigned int u32;

#define D_MODEL 1024
#define N_HEADS 16
#define D_HEAD  64
#define N_BINS  64
#define D_LAT   8

// ---------------------------------------------------------------------------
// bf16 split helpers (RTNE)
// ---------------------------------------------------------------------------
__device__ __forceinline__ unsigned short bf16_rtne(float f) {
    unsigned int u = __builtin_bit_cast(unsigned int, f);
    u += 0x7FFFu + ((u >> 16) & 1u);
    return (unsigned short)(u >> 16);
}
__device__ __forceinline__ float bf16_to_f32(unsigned short h) {
    unsigned int u = ((unsigned int)h) << 16;
    return __builtin_bit_cast(float, u);
}
__device__ __forceinline__ u32 pack_hl(float v) {
    unsigned short h = bf16_rtne(v);
    unsigned short l = bf16_rtne(v - bf16_to_f32(h));
    return (u32)h | ((u32)l << 16);
}
// unpack 8 consecutive packed (hi | lo<<16) u32 -> hi-frag, lo-frag
__device__ __forceinline__ void unpack8(const u32* p, bf16x8& hf, bf16x8& lf) {
    u32x4 r0 = *(const u32x4*)p;
    u32x4 r1 = *(const u32x4*)(p + 4);
    u32x4 hv, lv;
    hv[0] = (r0[0] & 0xffffu) | (r0[1] << 16);  lv[0] = (r0[0] >> 16) | (r0[1] & 0xffff0000u);
    hv[1] = (r0[2] & 0xffffu) | (r0[3] << 16);  lv[1] = (r0[2] >> 16) | (r0[3] & 0xffff0000u);
    hv[2] = (r1[0] & 0xffffu) | (r1[1] << 16);  lv[2] = (r1[0] >> 16) | (r1[1] & 0xffff0000u);
    hv[3] = (r1[2] & 0xffffu) | (r1[3] << 16);  lv[3] = (r1[2] >> 16) | (r1[3] & 0xffff0000u);
    hf = __builtin_bit_cast(bf16x8, hv);
    lf = __builtin_bit_cast(bf16x8, lv);
}

// fp32 -> (hi, lo) bf16 buffers, 8 elems/thread
__global__ __launch_bounds__(256)
void split_bf16x2(const float* __restrict__ in, unsigned short* __restrict__ hi,
                  unsigned short* __restrict__ lo, int n8)
{
    int i = blockIdx.x * 256 + threadIdx.x;
    if (i >= n8) return;
    const f4* inp = (const f4*)in;
    f4 a = inp[2 * i];
    f4 b = inp[2 * i + 1];
    unsigned short hs[8], ls[8];
#pragma unroll
    for (int j = 0; j < 8; j++) {
        float v = (j < 4) ? a[j] : b[j - 4];
        unsigned short h = bf16_rtne(v);
        hs[j] = h;
        ls[j] = bf16_rtne(v - bf16_to_f32(h));
    }
    u32x4 ho, lv;
#pragma unroll
    for (int j = 0; j < 4; j++) {
        ho[j] = (unsigned int)hs[2 * j] | ((unsigned int)hs[2 * j + 1] << 16);
        lv[j] = (unsigned int)ls[2 * j] | ((unsigned int)ls[2 * j + 1] << 16);
    }
    ((u32x4*)hi)[i] = ho;
    ((u32x4*)lo)[i] = lv;
}

// ---------------------------------------------------------------------------
// Split-bf16 MFMA GEMM (NT): C[M,N] = (Ahi+Alo)[M,K] * (Whi+Wlo)[N,K]^T + bias
// 256x256 tile, BK=32, 512 threads (8 waves as 2Mx4N, each 128x64 out),
// double-buffered 128KB LDS via global_load_lds(16B), chunk-XOR swizzle.
// ---------------------------------------------------------------------------
__device__ __forceinline__ void glds16(const unsigned short* g, unsigned short* l) {
    __builtin_amdgcn_global_load_lds((const __attribute__((address_space(1))) void*)g,
                                     (__attribute__((address_space(3))) void*)l,
                                     16, 0, 0);
}

template<bool SPLIT>
__global__ __launch_bounds__(512)
void gemm_bf16x2_nt(const unsigned short* __restrict__ Ahi, const unsigned short* __restrict__ Alo,
                    const unsigned short* __restrict__ Bhi, const unsigned short* __restrict__ Blo,
                    const float* __restrict__ bias, float* __restrict__ C,
                    unsigned short* __restrict__ Chi, unsigned short* __restrict__ Clo,
                    int M, int N, int K)
{
    __shared__ unsigned short lds[2][4][8192];   // [dbuf][Ahi,Alo,Bhi,Blo][256r x 32k]

    const int tid  = threadIdx.x;
    const int lane = tid & 63;
    const int w    = tid >> 6;
    const int wm   = w >> 2;         // 0..1
    const int wn   = w & 3;          // 0..3
    const int bm   = blockIdx.x * 256;
    const int bn   = blockIdx.y * 256;

    // staging: seg s covers rows [s*16,s*16+16); wave w handles s = i*8+w.
    // LDS (row r, chunk cpos) holds global k-chunk (cpos ^ (r&3)).
    const int schunk = (lane & 3) ^ ((lane >> 2) & 3);
    size_t gA[2], gB[2];
    int    seg[2];
#pragma unroll
    for (int i = 0; i < 2; i++) {
        int s = i * 8 + w;
        int r = s * 16 + (lane >> 2);
        gA[i]  = (size_t)(bm + r) * K + schunk * 8;
        gB[i]  = (size_t)(bn + r) * K + schunk * 8;
        seg[i] = s * 512;            // ushort offset of 1KB segment
    }

    const int koff  = ((lane >> 4) ^ (lane & 3)) * 8;   // swizzled k-chunk (row&3 == lane&3)
    const int abase = (wm * 128 + (lane & 15)) * 32 + koff;
    const int bbase = (wn * 64  + (lane & 15)) * 32 + koff;

    f32x4 acc[8][4];
#pragma unroll
    for (int i = 0; i < 8; i++)
#pragma unroll
        for (int j = 0; j < 4; j++) acc[i][j] = (f32x4){0.f, 0.f, 0.f, 0.f};

    auto stage = [&](int bb, int kt) {
#pragma unroll
        for (int i = 0; i < 2; i++) {
            glds16(Ahi + gA[i] + kt, &lds[bb][0][seg[i]]);
            glds16(Alo + gA[i] + kt, &lds[bb][1][seg[i]]);
            glds16(Bhi + gB[i] + kt, &lds[bb][2][seg[i]]);
            glds16(Blo + gB[i] + kt, &lds[bb][3][seg[i]]);
        }
    };

    stage(0, 0);
    __syncthreads();

    const int nt = K / 32;
    for (int t = 0; t < nt; t++) {
        const int cur = t & 1;
        if (t + 1 < nt) stage(cur ^ 1, (t + 1) * 32);

        bf16x8 bhf[4], blf[4];
#pragma unroll
        for (int fn = 0; fn < 4; fn++) {
            bhf[fn] = *(const bf16x8*)&lds[cur][2][bbase + fn * 512];
            blf[fn] = *(const bf16x8*)&lds[cur][3][bbase + fn * 512];
        }
#pragma unroll
        for (int half = 0; half < 2; half++) {
            bf16x8 ahf[4], alf[4];
#pragma unroll
            for (int i = 0; i < 4; i++) {
                ahf[i] = *(const bf16x8*)&lds[cur][0][abase + (half * 4 + i) * 512];
                alf[i] = *(const bf16x8*)&lds[cur][1][abase + (half * 4 + i) * 512];
            }
#pragma unroll
            for (int i = 0; i < 4; i++)
#pragma unroll
                for (int fn = 0; fn < 4; fn++) {
                    f32x4 a = acc[half * 4 + i][fn];
                    a = __builtin_amdgcn_mfma_f32_16x16x32_bf16(ahf[i], bhf[fn], a, 0, 0, 0);
                    a = __builtin_amdgcn_mfma_f32_16x16x32_bf16(ahf[i], blf[fn], a, 0, 0, 0);
                    a = __builtin_amdgcn_mfma_f32_16x16x32_bf16(alf[i], bhf[fn], a, 0, 0, 0);
                    acc[half * 4 + i][fn] = a;
                }
        }
        __syncthreads();
    }

    // epilogue: C/D layout col = lane&15, row = (lane>>4)*4 + e
    const int rb = bm + wm * 128;
    const int cb = bn + wn * 64;
    float bv[4];
#pragma unroll
    for (int fn = 0; fn < 4; fn++) bv[fn] = bias[cb + fn * 16 + (lane & 15)];
#pragma unroll
    for (int fm = 0; fm < 8; fm++)
#pragma unroll
        for (int e = 0; e < 4; e++) {
            size_t row = (size_t)(rb + fm * 16 + (lane >> 4) * 4 + e);
            if constexpr (SPLIT) {
#pragma unroll
                for (int fn = 0; fn < 4; fn++) {
                    float v = acc[fm][fn][e] + bv[fn];
                    unsigned short h = bf16_rtne(v);
                    Chi[row * N + cb + fn * 16 + (lane & 15)] = h;
                    Clo[row * N + cb + fn * 16 + (lane & 15)] = bf16_rtne(v - bf16_to_f32(h));
                }
            } else {
                float* cp = &C[row * N];
#pragma unroll
                for (int fn = 0; fn < 4; fn++)
                    cp[cb + fn * 16 + (lane & 15)] = acc[fm][fn][e] + bv[fn];
            }
        }
}

// ---------------------------------------------------------------------------
// Bin assignment + soft aggregation, aggregation now on MFMA.
// grid = (B*H, CH), 256 threads (4 waves). Per 64-row chunk:
//   stage K/V rows (f32 Kt for z-path) + transposed packed bf16 hi/lo KT32/VT32
//   z + softmax (VALU, as before) -> P32T[n][s] packed hi/lo + fp32 counts
//   aggregation: C[n][d] += P^T K (and V) via 3-term mfma_16x16x32_bf16;
//   wave w: matrix = w>>1 (0=K,1=V), d-cols (w&1)*32..+32 (8 frags/wave).
// partial layout per (bh,chunk): [Kacc 4096][Vacc 4096][cnt 4x64] = 8448.
// ---------------------------------------------------------------------------
__global__ __launch_bounds__(256)
void bin_assign_agg(const float* __restrict__ Kbuf, const float* __restrict__ Vbuf,
                    const float* __restrict__ W_bin, const float* __restrict__ proto,
                    const float* __restrict__ log_tau,
                    float* __restrict__ partials, int B, int S)
{
    __shared__ __attribute__((aligned(16))) float Wb[8][64];
    __shared__ __attribute__((aligned(16))) float Prt[8][64];
    __shared__ __attribute__((aligned(16))) float zsm[64][8];
    __shared__ __attribute__((aligned(16))) float Kt[64][68];
    __shared__ __attribute__((aligned(16))) u32 KT32[64][68];   // [d][s] packed hi|lo
    __shared__ __attribute__((aligned(16))) u32 VT32[64][68];
    __shared__ __attribute__((aligned(16))) u32 P32T[64][68];   // [n][s] packed hi|lo

    const int bh = blockIdx.x;
    const int h  = bh & (N_HEADS - 1);
    const int b  = bh >> 4;
    const int chunk = blockIdx.y;
    const int CH = gridDim.y;
    const int tid = threadIdx.x;
    const int lane = tid & 63;
    const int w = tid >> 6;

    if (tid < 128) {
        ((f4*)&Wb[0][0])[tid] = ((const f4*)W_bin)[tid];
    } else {
        int t = tid - 128;
        f4 p = ((const f4*)(proto + (size_t)h * N_BINS * D_LAT))[t];
        int n = t >> 1, l4 = (t & 1) * 4;
        Prt[l4 + 0][n] = p[0];
        Prt[l4 + 1][n] = p[1];
        Prt[l4 + 2][n] = p[2];
        Prt[l4 + 3][n] = p[3];
    }
    const float tau   = fmaxf(expf(log_tau[h]), 1e-3f);
    const float scale = 1.0f / (tau + 1e-8f);

    const int row = tid >> 2, sub = tid & 3;   // softmax: 4 lanes per key row
    const int lr = lane & 15, lc = lane >> 4;  // MFMA fragment indices
    const int mat = w >> 1;                    // 0 = K, 1 = V
    const int fn0 = (w & 1) * 2;               // d fragment pair

    f32x4 acc[4][2];
    f4 cntv[4];
#pragma unroll
    for (int i = 0; i < 4; i++) {
        cntv[i] = (f4){0.f, 0.f, 0.f, 0.f};
        acc[i][0] = (f32x4){0.f, 0.f, 0.f, 0.f};
        acc[i][1] = (f32x4){0.f, 0.f, 0.f, 0.f};
    }

    const int SC = S / CH;
    const int s_base = chunk * SC;

    for (int s0 = 0; s0 < SC; s0 += 64) {
        __syncthreads();   // previous chunk's MFMA reads done before restage
        // ---- stage: row-pairs; f32 rows for z-path + transposed bf16 hi/lo ----
#pragma unroll
        for (int q = 0; q < 2; q++) {
            int item = tid + 256 * q;       // 0..511
            int rp = item >> 4;             // 0..31
            int dc = item & 15;
            int r0 = rp * 2;
            size_t gi = ((size_t)(b * S + s_base + s0 + r0)) * D_MODEL + h * D_HEAD + dc * 4;
            f4 k0 = *(const f4*)&Kbuf[gi];
            f4 k1 = *(const f4*)&Kbuf[gi + D_MODEL];
            f4 v0 = *(const f4*)&Vbuf[gi];
            f4 v1 = *(const f4*)&Vbuf[gi + D_MODEL];
            *(f4*)&Kt[r0][dc * 4]     = k0;
            *(f4*)&Kt[r0 + 1][dc * 4] = k1;
#pragma unroll
            for (int j = 0; j < 4; j++) {
                int d = dc * 4 + j;
                *(u32x2*)&KT32[d][r0] = (u32x2){pack_hl(k0[j]), pack_hl(k1[j])};
                *(u32x2*)&VT32[d][r0] = (u32x2){pack_hl(v0[j]), pack_hl(v1[j])};
            }
        }
        __syncthreads();

        // ---- z[l] = K_row . W_bin[l] (2 l's per lane) ----
        {
            const int l0 = sub * 2;
            f4 z0 = {0.f, 0.f, 0.f, 0.f}, z1 = {0.f, 0.f, 0.f, 0.f};
#pragma unroll
            for (int d4 = 0; d4 < 16; d4++) {
                f4 kv = *(const f4*)&Kt[row][d4 * 4];
                f4 w0 = *(const f4*)&Wb[l0][d4 * 4];
                f4 w1 = *(const f4*)&Wb[l0 + 1][d4 * 4];
                z0 += kv * w0;
                z1 += kv * w1;
            }
            zsm[row][l0]     = z0[0] + z0[1] + z0[2] + z0[3];
            zsm[row][l0 + 1] = z1[0] + z1[1] + z1[2] + z1[3];
        }
        __syncthreads();

        // ---- logits + softmax over 64 bins; write P^T packed; counts ----
        {
            float zr[8];
#pragma unroll
            for (int l = 0; l < 8; l++) zr[l] = zsm[row][l];
            f4 lg[4];
#pragma unroll
            for (int q = 0; q < 4; q++) lg[q] = (f4){0.f, 0.f, 0.f, 0.f};
#pragma unroll
            for (int l = 0; l < 8; l++) {
                float zv = zr[l];
#pragma unroll
                for (int q = 0; q < 4; q++) {
                    f4 pr = *(const f4*)&Prt[l][sub * 16 + q * 4];
                    lg[q] += zv * pr;
                }
            }
            float mx = -1e30f;
#pragma unroll
            for (int q = 0; q < 4; q++) {
                lg[q] *= scale;
                mx = fmaxf(mx, fmaxf(fmaxf(lg[q][0], lg[q][1]), fmaxf(lg[q][2], lg[q][3])));
            }
            mx = fmaxf(mx, __shfl_xor(mx, 1));
            mx = fmaxf(mx, __shfl_xor(mx, 2));
            float sum = 0.f;
            f4 pv[4];
#pragma unroll
            for (int q = 0; q < 4; q++) {
#pragma unroll
                for (int e = 0; e < 4; e++) {
                    float ev = expf(lg[q][e] - mx);
                    pv[q][e] = ev;
                    sum += ev;
                }
            }
            sum += __shfl_xor(sum, 1);
            sum += __shfl_xor(sum, 2);
            float inv = 1.0f / sum;
#pragma unroll
            for (int q = 0; q < 4; q++) {
                pv[q] *= inv;
                cntv[q] += pv[q];
#pragma unroll
                for (int e = 0; e < 4; e++)
                    P32T[sub * 16 + q * 4 + e][row] = pack_hl(pv[q][e]);
            }
        }
        __syncthreads();

        // ---- MFMA aggregation: acc[n][d] += P^T (x) K/V over s=64 ----
#pragma unroll
        for (int ks = 0; ks < 2; ks++) {
            bf16x8 pah[4], pal[4];
#pragma unroll
            for (int fm = 0; fm < 4; fm++)
                unpack8(&P32T[fm * 16 + lr][ks * 32 + lc * 8], pah[fm], pal[fm]);
#pragma unroll
            for (int fnL = 0; fnL < 2; fnL++) {
                int dr = (fn0 + fnL) * 16 + lr;
                bf16x8 bhf, blf;
                const u32* bp = mat ? &VT32[dr][ks * 32 + lc * 8]
                                    : &KT32[dr][ks * 32 + lc * 8];
                unpack8(bp, bhf, blf);
#pragma unroll
                for (int fm = 0; fm < 4; fm++) {
                    f32x4 a = acc[fm][fnL];
                    a = __builtin_amdgcn_mfma_f32_16x16x32_bf16(pah[fm], bhf, a, 0, 0, 0);
                    a = __builtin_amdgcn_mfma_f32_16x16x32_bf16(pah[fm], blf, a, 0, 0, 0);
                    a = __builtin_amdgcn_mfma_f32_16x16x32_bf16(pal[fm], bhf, a, 0, 0, 0);
                    acc[fm][fnL] = a;
                }
            }
        }
    }

    // ---- counts: reduce the wave's 16 same-sub lanes ----
#pragma unroll
    for (int q = 0; q < 4; q++)
#pragma unroll
        for (int e = 0; e < 4; e++) {
            float c = cntv[q][e];
            c += __shfl_xor(c, 4);
            c += __shfl_xor(c, 8);
            c += __shfl_xor(c, 16);
            c += __shfl_xor(c, 32);
            cntv[q][e] = c;
        }

    float* base = partials + ((size_t)bh * CH + chunk) * 8448;
#pragma unroll
    for (int fm = 0; fm < 4; fm++)
#pragma unroll
        for (int fnL = 0; fnL < 2; fnL++)
#pragma unroll
            for (int e = 0; e < 4; e++) {
                int n = fm * 16 + lc * 4 + e;
                int d = (fn0 + fnL) * 16 + lr;
                base[mat * 4096 + (size_t)n * 64 + d] = acc[fm][fnL][e];
            }
    if ((lane >> 2) == 0) {   // lanes 0..3, sub = lane
#pragma unroll
        for (int q = 0; q < 4; q++)
#pragma unroll
            for (int e = 0; e < 4; e++)
                base[8192 + w * 64 + sub * 16 + q * 4 + e] = cntv[q][e];
    }
}

// ---------------------------------------------------------------------------
// Reduce partials -> bf16 hi/lo K_binned [bh][n][d] and V_binned^T [bh][d][n].
// FAITHFUL to reference broadcast bug: feature d divided by counts[d].
// ---------------------------------------------------------------------------
__global__ __launch_bounds__(256)
void bin_reduce(const float* __restrict__ partials,
                u16* __restrict__ Kbh, u16* __restrict__ Kbl,
                u16* __restrict__ Vth, u16* __restrict__ Vtl, int CH)
{
    const int bh = blockIdx.x;
    const int tid = threadIdx.x;
    __shared__ float inv_cnt[64];
    const float* base = partials + (size_t)bh * CH * 8448;
    if (tid < 64) {
        float c = 0.f;
        for (int ch = 0; ch < CH; ch++)
#pragma unroll
            for (int ww = 0; ww < 4; ww++)
                c += base[(size_t)ch * 8448 + 8192 + ww * 64 + tid];
        inv_cnt[tid] = 1.0f / (c + 1e-6f);
    }
    __syncthreads();
    for (int idx = tid; idx < 4096; idx += 256) {
        float k = 0.f, v = 0.f;
        for (int ch = 0; ch < CH; ch++) {
            const float* p = base + (size_t)ch * 8448;
            k += p[idx];
            v += p[4096 + idx];
        }
        float ic = inv_cnt[idx & 63];   // divide by count of FEATURE index d
        k *= ic;
        v *= ic;
        int n = idx >> 6, d = idx & 63;
        u16 kh = bf16_rtne(k);
        Kbh[(size_t)bh * 4096 + idx] = kh;
        Kbl[(size_t)bh * 4096 + idx] = bf16_rtne(k - bf16_to_f32(kh));
        u16 vh = bf16_rtne(v);
        size_t ti = (size_t)bh * 4096 + (size_t)d * 64 + n;   // transposed
        Vth[ti] = vh;
        Vtl[ti] = bf16_rtne(v - bf16_to_f32(vh));
    }
}

// ---------------------------------------------------------------------------
// Bin attention via bf16x2 MFMA (unchanged from round 3, passing).
// ---------------------------------------------------------------------------
__global__ __launch_bounds__(256)
void bin_attn_mfma(const u16* __restrict__ Qhi, const u16* __restrict__ Qlo,
                   const u16* __restrict__ Kbh, const u16* __restrict__ Kbl,
                   const u16* __restrict__ Vth, const u16* __restrict__ Vtl,
                   u16* __restrict__ ctx_hi, u16* __restrict__ ctx_lo,
                   int B, int S)
{
    __shared__ unsigned int P32[4][64][68];

    const int bh = blockIdx.x;
    const int h  = bh & (N_HEADS - 1);
    const int b  = bh >> 4;
    const int tid = threadIdx.x;
    const int l  = tid & 63;
    const int w  = tid >> 6;
    const int s0 = blockIdx.y * 256 + w * 64;

    const int lr = l & 15;
    const int lc = l >> 4;

    const size_t qoff  = ((size_t)(b * S + s0 + lr)) * D_MODEL + h * D_HEAD + lc * 8;
    const size_t kboff = (size_t)bh * 4096 + (size_t)lr * 64 + lc * 8;

    f32x4 acc[4][4];
#pragma unroll
    for (int i = 0; i < 4; i++)
#pragma unroll
        for (int j = 0; j < 4; j++) acc[i][j] = (f32x4){0.f, 0.f, 0.f, 0.f};

#pragma unroll
    for (int ks = 0; ks < 2; ks++) {
        bf16x8 qh[4], ql[4], kh[4], kl[4];
#pragma unroll
        for (int f = 0; f < 4; f++) {
            qh[f] = *(const bf16x8*)(Qhi + qoff + f * 16 * D_MODEL + ks * 32);
            ql[f] = *(const bf16x8*)(Qlo + qoff + f * 16 * D_MODEL + ks * 32);
            kh[f] = *(const bf16x8*)(Kbh + kboff + f * 1024 + ks * 32);
            kl[f] = *(const bf16x8*)(Kbl + kboff + f * 1024 + ks * 32);
        }
#pragma unroll
        for (int fm = 0; fm < 4; fm++)
#pragma unroll
            for (int fn = 0; fn < 4; fn++) {
                acc[fm][fn] = __builtin_amdgcn_mfma_f32_16x16x32_bf16(qh[fm], kh[fn], acc[fm][fn], 0, 0, 0);
                acc[fm][fn] = __builtin_amdgcn_mfma_f32_16x16x32_bf16(qh[fm], kl[fn], acc[fm][fn], 0, 0, 0);
                acc[fm][fn] = __builtin_amdgcn_mfma_f32_16x16x32_bf16(ql[fm], kh[fn], acc[fm][fn], 0, 0, 0);
            }
    }

#pragma unroll
    for (int fm = 0; fm < 4; fm++) {
#pragma unroll
        for (int e = 0; e < 4; e++) {
            float v0 = acc[fm][0][e] * 0.125f;
            float v1 = acc[fm][1][e] * 0.125f;
            float v2 = acc[fm][2][e] * 0.125f;
            float v3 = acc[fm][3][e] * 0.125f;
            float mx = fmaxf(fmaxf(v0, v1), fmaxf(v2, v3));
            mx = fmaxf(mx, __shfl_xor(mx, 1));
            mx = fmaxf(mx, __shfl_xor(mx, 2));
            mx = fmaxf(mx, __shfl_xor(mx, 4));
            mx = fmaxf(mx, __shfl_xor(mx, 8));
            float e0 = expf(v0 - mx), e1 = expf(v1 - mx);
            float e2 = expf(v2 - mx), e3 = expf(v3 - mx);
            float sum = e0 + e1 + e2 + e3;
            sum += __shfl_xor(sum, 1);
            sum += __shfl_xor(sum, 2);
            sum += __shfl_xor(sum, 4);
            sum += __shfl_xor(sum, 8);
            float inv = 1.0f / sum;
            float pv[4] = {e0 * inv, e1 * inv, e2 * inv, e3 * inv};
            int rowi = fm * 16 + lc * 4 + e;
#pragma unroll
            for (int fn = 0; fn < 4; fn++)
                P32[w][rowi][fn * 16 + lr] = pack_hl(pv[fn]);
        }
    }
    // only intra-wave LDS dependency (each wave owns P32[w])

    f32x4 acc2[4][4];
#pragma unroll
    for (int i = 0; i < 4; i++)
#pragma unroll
        for (int j = 0; j < 4; j++) acc2[i][j] = (f32x4){0.f, 0.f, 0.f, 0.f};

#pragma unroll
    for (int ks = 0; ks < 2; ks++) {
        bf16x8 vh[4], vl[4];
#pragma unroll
        for (int f = 0; f < 4; f++) {
            vh[f] = *(const bf16x8*)(Vth + kboff + f * 1024 + ks * 32);
            vl[f] = *(const bf16x8*)(Vtl + kboff + f * 1024 + ks * 32);
        }
        bf16x8 ph[4], pl[4];
#pragma unroll
        for (int fm = 0; fm < 4; fm++)
            unpack8(&P32[w][fm * 16 + lr][ks * 32 + lc * 8], ph[fm], pl[fm]);
#pragma unroll
        for (int fm = 0; fm < 4; fm++)
#pragma unroll
            for (int fn = 0; fn < 4; fn++) {
                acc2[fm][fn] = __builtin_amdgcn_mfma_f32_16x16x32_bf16(ph[fm], vh[fn], acc2[fm][fn], 0, 0, 0);
                acc2[fm][fn] = __builtin_amdgcn_mfma_f32_16x16x32_bf16(ph[fm], vl[fn], acc2[fm][fn], 0, 0, 0);
                acc2[fm][fn] = __builtin_amdgcn_mfma_f32_16x16x32_bf16(pl[fm], vh[fn], acc2[fm][fn], 0, 0, 0);
            }
    }

    const size_t gbase = ((size_t)(b * S + s0 + lc * 4)) * D_MODEL + h * D_HEAD + lr;
#pragma unroll
    for (int fm = 0; fm < 4; fm++)
#pragma unroll
        for (int e = 0; e < 4; e++) {
            size_t ro = gbase + ((size_t)(fm * 16 + e)) * D_MODEL;
#pragma unroll
            for (int fn = 0; fn < 4; fn++) {
                float v = acc2[fm][fn][e];
                u16 hv = bf16_rtne(v);
                ctx_hi[ro + fn * 16] = hv;
                ctx_lo[ro + fn * 16] = bf16_rtne(v - bf16_to_f32(hv));
            }
        }
}

// ---------------------------------------------------------------------------
extern "C" void kernel_launch(void* const* d_in, const int* in_sizes, int n_in,
                              void* d_out, int out_size, void* d_ws, size_t ws_size,
                              hipStream_t stream)
{
    (void)n_in; (void)out_size; (void)ws_size;
    const float* x       = (const float*)d_in[0];
    const float* Wq      = (const float*)d_in[1];
    const float* bq      = (const float*)d_in[2];
    const float* Wk      = (const float*)d_in[3];
    const float* bk      = (const float*)d_in[4];
    const float* Wv      = (const float*)d_in[5];
    const float* bv      = (const float*)d_in[6];
    const float* Wo      = (const float*)d_in[7];
    const float* bo      = (const float*)d_in[8];
    const float* W_bin   = (const float*)d_in[9];
    const float* proto   = (const float*)d_in[10];
    const float* log_tau = (const float*)d_in[11];
    float* out = (float*)d_out;

    const int M  = in_sizes[0] / D_MODEL;   // B*S = 16384
    const int S  = 4096;
    const int B  = M / S;                   // 4
    const int BH = B * N_HEADS;             // 64
    const int CH = 8;

    const size_t MB = (size_t)1 << 20;
    char* wsb = (char*)d_ws;
    float*          R1   = (float*)wsb;                        // 64 MB: K fp32, later Q hi/lo
    float*          R2   = (float*)(wsb + 64  * MB);           // 64 MB: V fp32
    unsigned short* XShi = (unsigned short*)(wsb + 128 * MB);  // 32 MB: x_hi -> ctx_hi
    unsigned short* XSlo = (unsigned short*)(wsb + 160 * MB);  // 32 MB: x_lo -> ctx_lo
    unsigned short* Whi  = (unsigned short*)(wsb + 192 * MB);  //  2 MB (reused per weight)
    unsigned short* Wlo  = (unsigned short*)(wsb + 194 * MB);  //  2 MB
    u16*            Kbh  = (u16*)(wsb + 196 * MB);             // 512 KB each
    u16*            Kbl  = Kbh + (size_t)BH * 4096;
    u16*            Vth  = Kbl + (size_t)BH * 4096;
    u16*            Vtl  = Vth + (size_t)BH * 4096;

    // partials (17.3 MB) scratch lives in d_out: fully written by bin_assign_agg,
    // consumed by bin_reduce, then d_out is overwritten by the final GEMM.
    float* part = (float*)d_out;

    u16* Qhi = (u16*)R1;                       // Q hi/lo overlay R1 (K fp32 dead)
    u16* Qlo = Qhi + (size_t)M * D_MODEL;

    const int n8x = (M * D_MODEL) / 8;
    const int n8w = (D_MODEL * D_MODEL) / 8;
    dim3 gg(M / 256, D_MODEL / 256);           // (64, 4)

    split_bf16x2<<<n8x / 256, 256, 0, stream>>>(x, XShi, XSlo, n8x);

    split_bf16x2<<<n8w / 256, 256, 0, stream>>>(Wk, Whi, Wlo, n8w);
    gemm_bf16x2_nt<false><<<gg, 512, 0, stream>>>(XShi, XSlo, Whi, Wlo, bk, R1,
                                                  nullptr, nullptr, M, D_MODEL, D_MODEL);

    split_bf16x2<<<n8w / 256, 256, 0, stream>>>(Wv, Whi, Wlo, n8w);
    gemm_bf16x2_nt<false><<<gg, 512, 0, stream>>>(XShi, XSlo, Whi, Wlo, bv, R2,
                                                  nullptr, nullptr, M, D_MODEL, D_MODEL);

    bin_assign_agg<<<dim3(BH, CH), 256, 0, stream>>>(R1, R2, W_bin, proto,
                                                     log_tau, part, B, S);
    bin_reduce<<<BH, 256, 0, stream>>>(part, Kbh, Kbl, Vth, Vtl, CH);

    // Q projection writes bf16 hi/lo directly (R1's fp32 K is consumed above)
    split_bf16x2<<<n8w / 256, 256, 0, stream>>>(Wq, Whi, Wlo, n8w);
    gemm_bf16x2_nt<true><<<gg, 512, 0, stream>>>(XShi, XSlo, Whi, Wlo, bq, nullptr,
                                                 Qhi, Qlo, M, D_MODEL, D_MODEL);

    // ctx hi/lo overwrite XShi/XSlo (x splits dead after Q GEMM)
    bin_attn_mfma<<<dim3(BH, S / 256), 256, 0, stream>>>(Qhi, Qlo, Kbh, Kbl, Vth, Vtl,
                                                         XShi, XSlo, B, S);

    split_bf16x2<<<n8w / 256, 256, 0, stream>>>(Wo, Whi, Wlo, n8w);
    gemm_bf16x2_nt<false><<<gg, 512, 0, stream>>>(XShi, XSlo, Whi, Wlo, bo, out,
                                                  nullptr, nullptr, M, D_MODEL, D_MODEL);
}

// Round 6
// 499.686 us; speedup vs baseline: 3.4250x; 1.0265x over previous
//
#include <hip/hip_runtime.h>
#include <math.h>

typedef float f4 __attribute__((ext_vector_type(4)));
typedef float f32x4 __attribute__((ext_vector_type(4)));
typedef short bf16x8 __attribute__((ext_vector_type(8)));
typedef unsigned int u32x4 __attribute__((ext_vector_type(4)));
typedef unsigned int u32x2 __attribute__((ext_vector_type(2)));
typedef unsigned short u16;
typedef unsigned int u32;

#define D_MODEL 1024
#define N_HEADS 16
#define D_HEAD  64
#define N_BINS  64
#define D_LAT   8

// ---------------------------------------------------------------------------
// bf16 split helpers (RTNE)
// ---------------------------------------------------------------------------
__device__ __forceinline__ unsigned short bf16_rtne(float f) {
    unsigned int u = __builtin_bit_cast(unsigned int, f);
    u += 0x7FFFu + ((u >> 16) & 1u);
    return (unsigned short)(u >> 16);
}
__device__ __forceinline__ float bf16_to_f32(unsigned short h) {
    unsigned int u = ((unsigned int)h) << 16;
    return __builtin_bit_cast(float, u);
}
__device__ __forceinline__ u32 pack_hl(float v) {
    unsigned short h = bf16_rtne(v);
    unsigned short l = bf16_rtne(v - bf16_to_f32(h));
    return (u32)h | ((u32)l << 16);
}
// unpack 8 consecutive packed (hi | lo<<16) u32 -> hi-frag, lo-frag
__device__ __forceinline__ void unpack8(const u32* p, bf16x8& hf, bf16x8& lf) {
    u32x4 r0 = *(const u32x4*)p;
    u32x4 r1 = *(const u32x4*)(p + 4);
    u32x4 hv, lv;
    hv[0] = (r0[0] & 0xffffu) | (r0[1] << 16);  lv[0] = (r0[0] >> 16) | (r0[1] & 0xffff0000u);
    hv[1] = (r0[2] & 0xffffu) | (r0[3] << 16);  lv[1] = (r0[2] >> 16) | (r0[3] & 0xffff0000u);
    hv[2] = (r1[0] & 0xffffu) | (r1[1] << 16);  lv[2] = (r1[0] >> 16) | (r1[1] & 0xffff0000u);
    hv[3] = (r1[2] & 0xffffu) | (r1[3] << 16);  lv[3] = (r1[2] >> 16) | (r1[3] & 0xffff0000u);
    hf = __builtin_bit_cast(bf16x8, hv);
    lf = __builtin_bit_cast(bf16x8, lv);
}

// fp32 -> (hi, lo) bf16 buffers, 8 elems/thread
__global__ __launch_bounds__(256)
void split_bf16x2(const float* __restrict__ in, unsigned short* __restrict__ hi,
                  unsigned short* __restrict__ lo, int n8)
{
    int i = blockIdx.x * 256 + threadIdx.x;
    if (i >= n8) return;
    const f4* inp = (const f4*)in;
    f4 a = inp[2 * i];
    f4 b = inp[2 * i + 1];
    unsigned short hs[8], ls[8];
#pragma unroll
    for (int j = 0; j < 8; j++) {
        float v = (j < 4) ? a[j] : b[j - 4];
        unsigned short h = bf16_rtne(v);
        hs[j] = h;
        ls[j] = bf16_rtne(v - bf16_to_f32(h));
    }
    u32x4 ho, lv;
#pragma unroll
    for (int j = 0; j < 4; j++) {
        ho[j] = (unsigned int)hs[2 * j] | ((unsigned int)hs[2 * j + 1] << 16);
        lv[j] = (unsigned int)ls[2 * j] | ((unsigned int)ls[2 * j + 1] << 16);
    }
    ((u32x4*)hi)[i] = ho;
    ((u32x4*)lo)[i] = lv;
}

// all four weight matrices -> one concat hi/lo buffer (order q,k,v,o),
// single launch replaces 4 small split launches.
__global__ __launch_bounds__(256)
void split4_w(const float* __restrict__ w0, const float* __restrict__ w1,
              const float* __restrict__ w2, const float* __restrict__ w3,
              unsigned short* __restrict__ hi, unsigned short* __restrict__ lo)
{
    const int which = blockIdx.y;
    const float* in = (which == 0) ? w0 : (which == 1) ? w1 : (which == 2) ? w2 : w3;
    int i = blockIdx.x * 256 + threadIdx.x;          // item of 8 elems
    const f4* inp = (const f4*)in;
    f4 a = inp[2 * i];
    f4 b = inp[2 * i + 1];
    unsigned short hs[8], ls[8];
#pragma unroll
    for (int j = 0; j < 8; j++) {
        float v = (j < 4) ? a[j] : b[j - 4];
        unsigned short h = bf16_rtne(v);
        hs[j] = h;
        ls[j] = bf16_rtne(v - bf16_to_f32(h));
    }
    u32x4 ho, lv;
#pragma unroll
    for (int j = 0; j < 4; j++) {
        ho[j] = (unsigned int)hs[2 * j] | ((unsigned int)hs[2 * j + 1] << 16);
        lv[j] = (unsigned int)ls[2 * j] | ((unsigned int)ls[2 * j + 1] << 16);
    }
    size_t off = (size_t)which * (D_MODEL * D_MODEL / 8);
    ((u32x4*)hi)[off + i] = ho;
    ((u32x4*)lo)[off + i] = lv;
}

// ---------------------------------------------------------------------------
// Split-bf16 MFMA GEMM (NT): C[M,N] = (Ahi+Alo)[M,K] * (Whi+Wlo)[N,K]^T + bias
// 256x256 tile, BK=32, 512 threads (8 waves as 2Mx4N, each 128x64 out),
// double-buffered 128KB LDS via global_load_lds(16B).
// Swizzle (both sides): LDS (row r, chunk slot c) holds global k-chunk
// c ^ ((r>>1)&3) — walks all 8 bank-quads over 8 rows => conflict-free
// ds_read_b128 (2 lanes/quad). Old row&3 key was 4-way conflicted (6.29M
// SQ_LDS_BANK_CONFLICT @ r5).
// ---------------------------------------------------------------------------
__device__ __forceinline__ void glds16(const unsigned short* g, unsigned short* l) {
    __builtin_amdgcn_global_load_lds((const __attribute__((address_space(1))) void*)g,
                                     (__attribute__((address_space(3))) void*)l,
                                     16, 0, 0);
}

template<bool SPLIT>
__global__ __launch_bounds__(512)
void gemm_bf16x2_nt(const unsigned short* __restrict__ Ahi, const unsigned short* __restrict__ Alo,
                    const unsigned short* __restrict__ Bhi, const unsigned short* __restrict__ Blo,
                    const float* __restrict__ bias, float* __restrict__ C,
                    unsigned short* __restrict__ Chi, unsigned short* __restrict__ Clo,
                    int M, int N, int K)
{
    __shared__ unsigned short lds[2][4][8192];   // [dbuf][Ahi,Alo,Bhi,Blo][256r x 32k]

    const int tid  = threadIdx.x;
    const int lane = tid & 63;
    const int w    = tid >> 6;
    const int wm   = w >> 2;         // 0..1
    const int wn   = w & 3;          // 0..3
    const int bm   = blockIdx.x * 256;
    const int bn   = blockIdx.y * 256;

    // staging: seg s covers rows [s*16,s*16+16); wave w handles s = i*8+w.
    // row-within-seg = lane>>2 => row bits 1..2 = (lane>>3)&3.
    const int schunk = (lane & 3) ^ ((lane >> 3) & 3);
    size_t gA[2], gB[2];
    int    seg[2];
#pragma unroll
    for (int i = 0; i < 2; i++) {
        int s = i * 8 + w;
        int r = s * 16 + (lane >> 2);
        gA[i]  = (size_t)(bm + r) * K + schunk * 8;
        gB[i]  = (size_t)(bn + r) * K + schunk * 8;
        seg[i] = s * 512;            // ushort offset of 1KB segment
    }

    // fragment read: row = base16 + (lane&15); slot = (lane>>4) ^ ((row>>1)&3)
    const int koff  = ((lane >> 4) ^ ((lane >> 1) & 3)) * 8;
    const int abase = (wm * 128 + (lane & 15)) * 32 + koff;
    const int bbase = (wn * 64  + (lane & 15)) * 32 + koff;

    f32x4 acc[8][4];
#pragma unroll
    for (int i = 0; i < 8; i++)
#pragma unroll
        for (int j = 0; j < 4; j++) acc[i][j] = (f32x4){0.f, 0.f, 0.f, 0.f};

    auto stage = [&](int bb, int kt) {
#pragma unroll
        for (int i = 0; i < 2; i++) {
            glds16(Ahi + gA[i] + kt, &lds[bb][0][seg[i]]);
            glds16(Alo + gA[i] + kt, &lds[bb][1][seg[i]]);
            glds16(Bhi + gB[i] + kt, &lds[bb][2][seg[i]]);
            glds16(Blo + gB[i] + kt, &lds[bb][3][seg[i]]);
        }
    };

    stage(0, 0);
    __syncthreads();

    const int nt = K / 32;
    for (int t = 0; t < nt; t++) {
        const int cur = t & 1;
        if (t + 1 < nt) stage(cur ^ 1, (t + 1) * 32);

        bf16x8 bhf[4], blf[4];
#pragma unroll
        for (int fn = 0; fn < 4; fn++) {
            bhf[fn] = *(const bf16x8*)&lds[cur][2][bbase + fn * 512];
            blf[fn] = *(const bf16x8*)&lds[cur][3][bbase + fn * 512];
        }
#pragma unroll
        for (int half = 0; half < 2; half++) {
            bf16x8 ahf[4], alf[4];
#pragma unroll
            for (int i = 0; i < 4; i++) {
                ahf[i] = *(const bf16x8*)&lds[cur][0][abase + (half * 4 + i) * 512];
                alf[i] = *(const bf16x8*)&lds[cur][1][abase + (half * 4 + i) * 512];
            }
#pragma unroll
            for (int i = 0; i < 4; i++)
#pragma unroll
                for (int fn = 0; fn < 4; fn++) {
                    f32x4 a = acc[half * 4 + i][fn];
                    a = __builtin_amdgcn_mfma_f32_16x16x32_bf16(ahf[i], bhf[fn], a, 0, 0, 0);
                    a = __builtin_amdgcn_mfma_f32_16x16x32_bf16(ahf[i], blf[fn], a, 0, 0, 0);
                    a = __builtin_amdgcn_mfma_f32_16x16x32_bf16(alf[i], bhf[fn], a, 0, 0, 0);
                    acc[half * 4 + i][fn] = a;
                }
        }
        __syncthreads();
    }

    // epilogue: C/D layout col = lane&15, row = (lane>>4)*4 + e
    const int rb = bm + wm * 128;
    const int cb = bn + wn * 64;
    float bv[4];
#pragma unroll
    for (int fn = 0; fn < 4; fn++) bv[fn] = bias[cb + fn * 16 + (lane & 15)];
#pragma unroll
    for (int fm = 0; fm < 8; fm++)
#pragma unroll
        for (int e = 0; e < 4; e++) {
            size_t row = (size_t)(rb + fm * 16 + (lane >> 4) * 4 + e);
            if constexpr (SPLIT) {
#pragma unroll
                for (int fn = 0; fn < 4; fn++) {
                    float v = acc[fm][fn][e] + bv[fn];
                    unsigned short h = bf16_rtne(v);
                    Chi[row * N + cb + fn * 16 + (lane & 15)] = h;
                    Clo[row * N + cb + fn * 16 + (lane & 15)] = bf16_rtne(v - bf16_to_f32(h));
                }
            } else {
                float* cp = &C[row * N];
#pragma unroll
                for (int fn = 0; fn < 4; fn++)
                    cp[cb + fn * 16 + (lane & 15)] = acc[fm][fn][e] + bv[fn];
            }
        }
}

// ---------------------------------------------------------------------------
// Bin assignment + soft aggregation (MFMA aggregation; unchanged from r5).
// ---------------------------------------------------------------------------
__global__ __launch_bounds__(256)
void bin_assign_agg(const float* __restrict__ Kbuf, const float* __restrict__ Vbuf,
                    const float* __restrict__ W_bin, const float* __restrict__ proto,
                    const float* __restrict__ log_tau,
                    float* __restrict__ partials, int B, int S)
{
    __shared__ __attribute__((aligned(16))) float Wb[8][64];
    __shared__ __attribute__((aligned(16))) float Prt[8][64];
    __shared__ __attribute__((aligned(16))) float zsm[64][8];
    __shared__ __attribute__((aligned(16))) float Kt[64][68];
    __shared__ __attribute__((aligned(16))) u32 KT32[64][68];   // [d][s] packed hi|lo
    __shared__ __attribute__((aligned(16))) u32 VT32[64][68];
    __shared__ __attribute__((aligned(16))) u32 P32T[64][68];   // [n][s] packed hi|lo

    const int bh = blockIdx.x;
    const int h  = bh & (N_HEADS - 1);
    const int b  = bh >> 4;
    const int chunk = blockIdx.y;
    const int CH = gridDim.y;
    const int tid = threadIdx.x;
    const int lane = tid & 63;
    const int w = tid >> 6;

    if (tid < 128) {
        ((f4*)&Wb[0][0])[tid] = ((const f4*)W_bin)[tid];
    } else {
        int t = tid - 128;
        f4 p = ((const f4*)(proto + (size_t)h * N_BINS * D_LAT))[t];
        int n = t >> 1, l4 = (t & 1) * 4;
        Prt[l4 + 0][n] = p[0];
        Prt[l4 + 1][n] = p[1];
        Prt[l4 + 2][n] = p[2];
        Prt[l4 + 3][n] = p[3];
    }
    const float tau   = fmaxf(expf(log_tau[h]), 1e-3f);
    const float scale = 1.0f / (tau + 1e-8f);

    const int row = tid >> 2, sub = tid & 3;   // softmax: 4 lanes per key row
    const int lr = lane & 15, lc = lane >> 4;  // MFMA fragment indices
    const int mat = w >> 1;                    // 0 = K, 1 = V
    const int fn0 = (w & 1) * 2;               // d fragment pair

    f32x4 acc[4][2];
    f4 cntv[4];
#pragma unroll
    for (int i = 0; i < 4; i++) {
        cntv[i] = (f4){0.f, 0.f, 0.f, 0.f};
        acc[i][0] = (f32x4){0.f, 0.f, 0.f, 0.f};
        acc[i][1] = (f32x4){0.f, 0.f, 0.f, 0.f};
    }

    const int SC = S / CH;
    const int s_base = chunk * SC;

    for (int s0 = 0; s0 < SC; s0 += 64) {
        __syncthreads();   // previous chunk's MFMA reads done before restage
#pragma unroll
        for (int q = 0; q < 2; q++) {
            int item = tid + 256 * q;       // 0..511
            int rp = item >> 4;             // 0..31
            int dc = item & 15;
            int r0 = rp * 2;
            size_t gi = ((size_t)(b * S + s_base + s0 + r0)) * D_MODEL + h * D_HEAD + dc * 4;
            f4 k0 = *(const f4*)&Kbuf[gi];
            f4 k1 = *(const f4*)&Kbuf[gi + D_MODEL];
            f4 v0 = *(const f4*)&Vbuf[gi];
            f4 v1 = *(const f4*)&Vbuf[gi + D_MODEL];
            *(f4*)&Kt[r0][dc * 4]     = k0;
            *(f4*)&Kt[r0 + 1][dc * 4] = k1;
#pragma unroll
            for (int j = 0; j < 4; j++) {
                int d = dc * 4 + j;
                *(u32x2*)&KT32[d][r0] = (u32x2){pack_hl(k0[j]), pack_hl(k1[j])};
                *(u32x2*)&VT32[d][r0] = (u32x2){pack_hl(v0[j]), pack_hl(v1[j])};
            }
        }
        __syncthreads();

        {
            const int l0 = sub * 2;
            f4 z0 = {0.f, 0.f, 0.f, 0.f}, z1 = {0.f, 0.f, 0.f, 0.f};
#pragma unroll
            for (int d4 = 0; d4 < 16; d4++) {
                f4 kv = *(const f4*)&Kt[row][d4 * 4];
                f4 w0 = *(const f4*)&Wb[l0][d4 * 4];
                f4 w1 = *(const f4*)&Wb[l0 + 1][d4 * 4];
                z0 += kv * w0;
                z1 += kv * w1;
            }
            zsm[row][l0]     = z0[0] + z0[1] + z0[2] + z0[3];
            zsm[row][l0 + 1] = z1[0] + z1[1] + z1[2] + z1[3];
        }
        __syncthreads();

        {
            float zr[8];
#pragma unroll
            for (int l = 0; l < 8; l++) zr[l] = zsm[row][l];
            f4 lg[4];
#pragma unroll
            for (int q = 0; q < 4; q++) lg[q] = (f4){0.f, 0.f, 0.f, 0.f};
#pragma unroll
            for (int l = 0; l < 8; l++) {
                float zv = zr[l];
#pragma unroll
                for (int q = 0; q < 4; q++) {
                    f4 pr = *(const f4*)&Prt[l][sub * 16 + q * 4];
                    lg[q] += zv * pr;
                }
            }
            float mx = -1e30f;
#pragma unroll
            for (int q = 0; q < 4; q++) {
                lg[q] *= scale;
                mx = fmaxf(mx, fmaxf(fmaxf(lg[q][0], lg[q][1]), fmaxf(lg[q][2], lg[q][3])));
            }
            mx = fmaxf(mx, __shfl_xor(mx, 1));
            mx = fmaxf(mx, __shfl_xor(mx, 2));
            float sum = 0.f;
            f4 pv[4];
#pragma unroll
            for (int q = 0; q < 4; q++) {
#pragma unroll
                for (int e = 0; e < 4; e++) {
                    float ev = expf(lg[q][e] - mx);
                    pv[q][e] = ev;
                    sum += ev;
                }
            }
            sum += __shfl_xor(sum, 1);
            sum += __shfl_xor(sum, 2);
            float inv = 1.0f / sum;
#pragma unroll
            for (int q = 0; q < 4; q++) {
                pv[q] *= inv;
                cntv[q] += pv[q];
#pragma unroll
                for (int e = 0; e < 4; e++)
                    P32T[sub * 16 + q * 4 + e][row] = pack_hl(pv[q][e]);
            }
        }
        __syncthreads();

#pragma unroll
        for (int ks = 0; ks < 2; ks++) {
            bf16x8 pah[4], pal[4];
#pragma unroll
            for (int fm = 0; fm < 4; fm++)
                unpack8(&P32T[fm * 16 + lr][ks * 32 + lc * 8], pah[fm], pal[fm]);
#pragma unroll
            for (int fnL = 0; fnL < 2; fnL++) {
                int dr = (fn0 + fnL) * 16 + lr;
                bf16x8 bhf, blf;
                const u32* bp = mat ? &VT32[dr][ks * 32 + lc * 8]
                                    : &KT32[dr][ks * 32 + lc * 8];
                unpack8(bp, bhf, blf);
#pragma unroll
                for (int fm = 0; fm < 4; fm++) {
                    f32x4 a = acc[fm][fnL];
                    a = __builtin_amdgcn_mfma_f32_16x16x32_bf16(pah[fm], bhf, a, 0, 0, 0);
                    a = __builtin_amdgcn_mfma_f32_16x16x32_bf16(pah[fm], blf, a, 0, 0, 0);
                    a = __builtin_amdgcn_mfma_f32_16x16x32_bf16(pal[fm], bhf, a, 0, 0, 0);
                    acc[fm][fnL] = a;
                }
            }
        }
    }

#pragma unroll
    for (int q = 0; q < 4; q++)
#pragma unroll
        for (int e = 0; e < 4; e++) {
            float c = cntv[q][e];
            c += __shfl_xor(c, 4);
            c += __shfl_xor(c, 8);
            c += __shfl_xor(c, 16);
            c += __shfl_xor(c, 32);
            cntv[q][e] = c;
        }

    float* base = partials + ((size_t)bh * CH + chunk) * 8448;
#pragma unroll
    for (int fm = 0; fm < 4; fm++)
#pragma unroll
        for (int fnL = 0; fnL < 2; fnL++)
#pragma unroll
            for (int e = 0; e < 4; e++) {
                int n = fm * 16 + lc * 4 + e;
                int d = (fn0 + fnL) * 16 + lr;
                base[mat * 4096 + (size_t)n * 64 + d] = acc[fm][fnL][e];
            }
    if ((lane >> 2) == 0) {   // lanes 0..3, sub = lane
#pragma unroll
        for (int q = 0; q < 4; q++)
#pragma unroll
            for (int e = 0; e < 4; e++)
                base[8192 + w * 64 + sub * 16 + q * 4 + e] = cntv[q][e];
    }
}

// ---------------------------------------------------------------------------
// Reduce partials -> bf16 hi/lo K_binned [bh][n][d] and V_binned^T [bh][d][n].
// FAITHFUL to reference broadcast bug: feature d divided by counts[d].
// ---------------------------------------------------------------------------
__global__ __launch_bounds__(256)
void bin_reduce(const float* __restrict__ partials,
                u16* __restrict__ Kbh, u16* __restrict__ Kbl,
                u16* __restrict__ Vth, u16* __restrict__ Vtl, int CH)
{
    const int bh = blockIdx.x;
    const int tid = threadIdx.x;
    __shared__ float inv_cnt[64];
    const float* base = partials + (size_t)bh * CH * 8448;
    if (tid < 64) {
        float c = 0.f;
        for (int ch = 0; ch < CH; ch++)
#pragma unroll
            for (int ww = 0; ww < 4; ww++)
                c += base[(size_t)ch * 8448 + 8192 + ww * 64 + tid];
        inv_cnt[tid] = 1.0f / (c + 1e-6f);
    }
    __syncthreads();
    for (int idx = tid; idx < 4096; idx += 256) {
        float k = 0.f, v = 0.f;
        for (int ch = 0; ch < CH; ch++) {
            const float* p = base + (size_t)ch * 8448;
            k += p[idx];
            v += p[4096 + idx];
        }
        float ic = inv_cnt[idx & 63];   // divide by count of FEATURE index d
        k *= ic;
        v *= ic;
        int n = idx >> 6, d = idx & 63;
        u16 kh = bf16_rtne(k);
        Kbh[(size_t)bh * 4096 + idx] = kh;
        Kbl[(size_t)bh * 4096 + idx] = bf16_rtne(k - bf16_to_f32(kh));
        u16 vh = bf16_rtne(v);
        size_t ti = (size_t)bh * 4096 + (size_t)d * 64 + n;   // transposed
        Vth[ti] = vh;
        Vtl[ti] = bf16_rtne(v - bf16_to_f32(vh));
    }
}

// ---------------------------------------------------------------------------
// Bin attention via bf16x2 MFMA (unchanged, passing).
// ---------------------------------------------------------------------------
__global__ __launch_bounds__(256)
void bin_attn_mfma(const u16* __restrict__ Qhi, const u16* __restrict__ Qlo,
                   const u16* __restrict__ Kbh, const u16* __restrict__ Kbl,
                   const u16* __restrict__ Vth, const u16* __restrict__ Vtl,
                   u16* __restrict__ ctx_hi, u16* __restrict__ ctx_lo,
                   int B, int S)
{
    __shared__ unsigned int P32[4][64][68];

    const int bh = blockIdx.x;
    const int h  = bh & (N_HEADS - 1);
    const int b  = bh >> 4;
    const int tid = threadIdx.x;
    const int l  = tid & 63;
    const int w  = tid >> 6;
    const int s0 = blockIdx.y * 256 + w * 64;

    const int lr = l & 15;
    const int lc = l >> 4;

    const size_t qoff  = ((size_t)(b * S + s0 + lr)) * D_MODEL + h * D_HEAD + lc * 8;
    const size_t kboff = (size_t)bh * 4096 + (size_t)lr * 64 + lc * 8;

    f32x4 acc[4][4];
#pragma unroll
    for (int i = 0; i < 4; i++)
#pragma unroll
        for (int j = 0; j < 4; j++) acc[i][j] = (f32x4){0.f, 0.f, 0.f, 0.f};

#pragma unroll
    for (int ks = 0; ks < 2; ks++) {
        bf16x8 qh[4], ql[4], kh[4], kl[4];
#pragma unroll
        for (int f = 0; f < 4; f++) {
            qh[f] = *(const bf16x8*)(Qhi + qoff + f * 16 * D_MODEL + ks * 32);
            ql[f] = *(const bf16x8*)(Qlo + qoff + f * 16 * D_MODEL + ks * 32);
            kh[f] = *(const bf16x8*)(Kbh + kboff + f * 1024 + ks * 32);
            kl[f] = *(const bf16x8*)(Kbl + kboff + f * 1024 + ks * 32);
        }
#pragma unroll
        for (int fm = 0; fm < 4; fm++)
#pragma unroll
            for (int fn = 0; fn < 4; fn++) {
                acc[fm][fn] = __builtin_amdgcn_mfma_f32_16x16x32_bf16(qh[fm], kh[fn], acc[fm][fn], 0, 0, 0);
                acc[fm][fn] = __builtin_amdgcn_mfma_f32_16x16x32_bf16(qh[fm], kl[fn], acc[fm][fn], 0, 0, 0);
                acc[fm][fn] = __builtin_amdgcn_mfma_f32_16x16x32_bf16(ql[fm], kh[fn], acc[fm][fn], 0, 0, 0);
            }
    }

#pragma unroll
    for (int fm = 0; fm < 4; fm++) {
#pragma unroll
        for (int e = 0; e < 4; e++) {
            float v0 = acc[fm][0][e] * 0.125f;
            float v1 = acc[fm][1][e] * 0.125f;
            float v2 = acc[fm][2][e] * 0.125f;
            float v3 = acc[fm][3][e] * 0.125f;
            float mx = fmaxf(fmaxf(v0, v1), fmaxf(v2, v3));
            mx = fmaxf(mx, __shfl_xor(mx, 1));
            mx = fmaxf(mx, __shfl_xor(mx, 2));
            mx = fmaxf(mx, __shfl_xor(mx, 4));
            mx = fmaxf(mx, __shfl_xor(mx, 8));
            float e0 = expf(v0 - mx), e1 = expf(v1 - mx);
            float e2 = expf(v2 - mx), e3 = expf(v3 - mx);
            float sum = e0 + e1 + e2 + e3;
            sum += __shfl_xor(sum, 1);
            sum += __shfl_xor(sum, 2);
            sum += __shfl_xor(sum, 4);
            sum += __shfl_xor(sum, 8);
            float inv = 1.0f / sum;
            float pv[4] = {e0 * inv, e1 * inv, e2 * inv, e3 * inv};
            int rowi = fm * 16 + lc * 4 + e;
#pragma unroll
            for (int fn = 0; fn < 4; fn++)
                P32[w][rowi][fn * 16 + lr] = pack_hl(pv[fn]);
        }
    }
    // only intra-wave LDS dependency (each wave owns P32[w])

    f32x4 acc2[4][4];
#pragma unroll
    for (int i = 0; i < 4; i++)
#pragma unroll
        for (int j = 0; j < 4; j++) acc2[i][j] = (f32x4){0.f, 0.f, 0.f, 0.f};

#pragma unroll
    for (int ks = 0; ks < 2; ks++) {
        bf16x8 vh[4], vl[4];
#pragma unroll
        for (int f = 0; f < 4; f++) {
            vh[f] = *(const bf16x8*)(Vth + kboff + f * 1024 + ks * 32);
            vl[f] = *(const bf16x8*)(Vtl + kboff + f * 1024 + ks * 32);
        }
        bf16x8 ph[4], pl[4];
#pragma unroll
        for (int fm = 0; fm < 4; fm++)
            unpack8(&P32[w][fm * 16 + lr][ks * 32 + lc * 8], ph[fm], pl[fm]);
#pragma unroll
        for (int fm = 0; fm < 4; fm++)
#pragma unroll
            for (int fn = 0; fn < 4; fn++) {
                acc2[fm][fn] = __builtin_amdgcn_mfma_f32_16x16x32_bf16(ph[fm], vh[fn], acc2[fm][fn], 0, 0, 0);
                acc2[fm][fn] = __builtin_amdgcn_mfma_f32_16x16x32_bf16(ph[fm], vl[fn], acc2[fm][fn], 0, 0, 0);
                acc2[fm][fn] = __builtin_amdgcn_mfma_f32_16x16x32_bf16(pl[fm], vh[fn], acc2[fm][fn], 0, 0, 0);
            }
    }

    const size_t gbase = ((size_t)(b * S + s0 + lc * 4)) * D_MODEL + h * D_HEAD + lr;
#pragma unroll
    for (int fm = 0; fm < 4; fm++)
#pragma unroll
        for (int e = 0; e < 4; e++) {
            size_t ro = gbase + ((size_t)(fm * 16 + e)) * D_MODEL;
#pragma unroll
            for (int fn = 0; fn < 4; fn++) {
                float v = acc2[fm][fn][e];
                u16 hv = bf16_rtne(v);
                ctx_hi[ro + fn * 16] = hv;
                ctx_lo[ro + fn * 16] = bf16_rtne(v - bf16_to_f32(hv));
            }
        }
}

// ---------------------------------------------------------------------------
extern "C" void kernel_launch(void* const* d_in, const int* in_sizes, int n_in,
                              void* d_out, int out_size, void* d_ws, size_t ws_size,
                              hipStream_t stream)
{
    (void)n_in; (void)out_size; (void)ws_size;
    const float* x       = (const float*)d_in[0];
    const float* Wq      = (const float*)d_in[1];
    const float* bq      = (const float*)d_in[2];
    const float* Wk      = (const float*)d_in[3];
    const float* bk      = (const float*)d_in[4];
    const float* Wv      = (const float*)d_in[5];
    const float* bv      = (const float*)d_in[6];
    const float* Wo      = (const float*)d_in[7];
    const float* bo      = (const float*)d_in[8];
    const float* W_bin   = (const float*)d_in[9];
    const float* proto   = (const float*)d_in[10];
    const float* log_tau = (const float*)d_in[11];
    float* out = (float*)d_out;

    const int M  = in_sizes[0] / D_MODEL;   // B*S = 16384
    const int S  = 4096;
    const int B  = M / S;                   // 4
    const int BH = B * N_HEADS;             // 64
    const int CH = 8;

    const size_t MB = (size_t)1 << 20;
    char* wsb = (char*)d_ws;
    float*          R1   = (float*)wsb;                        // 64 MB: K fp32, later Q hi/lo
    float*          R2   = (float*)(wsb + 64  * MB);           // 64 MB: V fp32
    unsigned short* XShi = (unsigned short*)(wsb + 128 * MB);  // 32 MB: x_hi -> ctx_hi
    unsigned short* XSlo = (unsigned short*)(wsb + 160 * MB);  // 32 MB: x_lo -> ctx_lo
    unsigned short* W4hi = (unsigned short*)(wsb + 192 * MB);  //  8 MB: q,k,v,o concat
    unsigned short* W4lo = (unsigned short*)(wsb + 200 * MB);  //  8 MB
    u16*            Kbh  = (u16*)(wsb + 208 * MB);             // 512 KB each
    u16*            Kbl  = Kbh + (size_t)BH * 4096;
    u16*            Vth  = Kbl + (size_t)BH * 4096;
    u16*            Vtl  = Vth + (size_t)BH * 4096;

    // partials (17.3 MB) scratch lives in d_out: fully written by bin_assign_agg,
    // consumed by bin_reduce, then d_out is overwritten by the final GEMM.
    float* part = (float*)d_out;

    u16* Qhi = (u16*)R1;                       // Q hi/lo overlay R1 (K fp32 dead)
    u16* Qlo = Qhi + (size_t)M * D_MODEL;

    const size_t WOFF = (size_t)D_MODEL * D_MODEL;   // per-weight offset in concat
    const int n8x = (M * D_MODEL) / 8;
    const int n8w = (D_MODEL * D_MODEL) / 8;
    dim3 gg(M / 256, D_MODEL / 256);           // (64, 4)

    split_bf16x2<<<n8x / 256, 256, 0, stream>>>(x, XShi, XSlo, n8x);
    split4_w<<<dim3(n8w / 256, 4), 256, 0, stream>>>(Wq, Wk, Wv, Wo, W4hi, W4lo);

    gemm_bf16x2_nt<false><<<gg, 512, 0, stream>>>(XShi, XSlo, W4hi + WOFF, W4lo + WOFF,
                                                  bk, R1, nullptr, nullptr,
                                                  M, D_MODEL, D_MODEL);
    gemm_bf16x2_nt<false><<<gg, 512, 0, stream>>>(XShi, XSlo, W4hi + 2 * WOFF, W4lo + 2 * WOFF,
                                                  bv, R2, nullptr, nullptr,
                                                  M, D_MODEL, D_MODEL);

    bin_assign_agg<<<dim3(BH, CH), 256, 0, stream>>>(R1, R2, W_bin, proto,
                                                     log_tau, part, B, S);
    bin_reduce<<<BH, 256, 0, stream>>>(part, Kbh, Kbl, Vth, Vtl, CH);

    // Q projection writes bf16 hi/lo directly (R1's fp32 K is consumed above)
    gemm_bf16x2_nt<true><<<gg, 512, 0, stream>>>(XShi, XSlo, W4hi, W4lo,
                                                 bq, nullptr, Qhi, Qlo,
                                                 M, D_MODEL, D_MODEL);

    // ctx hi/lo overwrite XShi/XSlo (x splits dead after Q GEMM)
    bin_attn_mfma<<<dim3(BH, S / 256), 256, 0, stream>>>(Qhi, Qlo, Kbh, Kbl, Vth, Vtl,
                                                         XShi, XSlo, B, S);

    gemm_bf16x2_nt<false><<<gg, 512, 0, stream>>>(XShi, XSlo, W4hi + 3 * WOFF, W4lo + 3 * WOFF,
                                                  bo, out, nullptr, nullptr,
                                                  M, D_MODEL, D_MODEL);
}